// Round 17
// baseline (130.704 us; speedup 1.0000x reference)
//
#include <hip/hip_runtime.h>
#include <stdint.h>

#define BATCH 16
#define NDET 25200
#define NCLS 80
#define PREDC 85
#define KTOP 2048
#define MAXDET 300
#define OUTC 86
#define CONF_THR 0.4f
#define IOU_THR 0.45f
#define MAXWH 4096.0f
#define INVHI 0xBF800000u       // ~mono(-1.0f): score word of invalid rows
#define BMW (NCLS * 64)         // class bitmap words per batch (80 classes x 64)
#define NB 8192                 // histogram bins (13 bits of hi-0x40000000)
#define SIDECAP 2048
#define QPB ((MAXDET * OUTC) / 4)   // 6450 float4 per batch
#define BPB ((QPB + 255) / 256)     // 26 blocks per batch

typedef float fx4 __attribute__((ext_vector_type(4)));

// ---- monotone float<->uint mapping (ascending) ----
__device__ __forceinline__ uint32_t mono_f32(float f) {
  uint32_t u = __float_as_uint(f);
  return (u & 0x80000000u) ? ~u : (u | 0x80000000u);
}
__device__ __forceinline__ float unmono_f32(uint32_t m) {
  uint32_t u = (m & 0x80000000u) ? (m & 0x7FFFFFFFu) : ~m;
  return __uint_as_float(u);
}

// K1: obj-gated score/argmax + fused pass-A histogram (round-16 lesson:
// k_sel's serial scans/FINDs were ~60us; move the histogram to the parallel
// kernel). Valid rows: direct global atomicAdd over ~1400 distinct bins.
// Invalid rows: block-aggregated single atomic to bin NB-1.
__global__ void __launch_bounds__(256) k_keys(const float* __restrict__ pred,
                                              uint32_t* __restrict__ sw,
                                              uint8_t* __restrict__ cls8,
                                              uint32_t* __restrict__ histA) {
  __shared__ uint32_t invc[2];
  if (threadIdx.x < 2) invc[threadIdx.x] = 0;
  __syncthreads();
  int gq = blockIdx.x * 64 + (threadIdx.x >> 2);   // 64 rows per block
  int q = threadIdx.x & 3;
  const float* row = pred + (size_t)gq * PREDC;
  float obj = row[4];
  float score = -1.0f;
  uint32_t cl = 0;
  if (obj > CONF_THR) {
    float best = -1e30f;
    int bc = 0;
#pragma unroll
    for (int k = 0; k < 5; ++k) {
#pragma unroll
      for (int j = 0; j < 4; ++j) {
        int c = k * 16 + q * 4 + j;                 // ascending within lane
        float s = __fmul_rn(row[5 + c], obj);       // single-rounded, no contraction
        if (s > best) { best = s; bc = c; }         // strict > : first max
      }
    }
    for (int d = 1; d <= 2; d <<= 1) {              // quad reduce
      float vo = __shfl_xor(best, d);
      int co = __shfl_xor(bc, d);
      if (vo > best || (vo == best && co < bc)) { best = vo; bc = co; }
    }
    if (best > CONF_THR) { score = best; cl = (uint32_t)bc; }
  }
  int b = gq / NDET;
  int b0 = (blockIdx.x * 64) / NDET;
  if (q == 0) {
    uint32_t hi = ~mono_f32(score);
    sw[gq] = hi;
    cls8[gq] = (uint8_t)cl;
    if (score > 0.0f)
      atomicAdd(&histA[(size_t)b * NB + ((hi - 0x40000000u) >> 13)], 1u);
    else
      atomicAdd(&invc[b - b0], 1u);
  }
  __syncthreads();
  if (threadIdx.x < 2) {
    uint32_t c = invc[threadIdx.x];
    if (c) atomicAdd(&histA[(size_t)(b0 + threadIdx.x) * NB + (NB - 1)], c);
  }
}

// K2: wave-parallel FIND on precomputed histA + ONE combined scan
// (main append bin<dA, side list bin==dA) + O(s^2) full-key side ranking
// (exactly resolves the 2048 boundary: key order = score desc, index asc) +
// hybrid register/LDS bitonic sort + derive (+ class bitmap).
__global__ void __launch_bounds__(1024) k_sel(
    const uint32_t* __restrict__ sw, const uint8_t* __restrict__ cls8,
    const float* __restrict__ pred, const uint32_t* __restrict__ histA,
    uint32_t* __restrict__ s_n, float* __restrict__ s_score, float* __restrict__ s_clsf,
    uint32_t* __restrict__ clsbm, float* __restrict__ s_box, float* __restrict__ s_obox,
    uint32_t* __restrict__ keepbm) {
  __shared__ uint64_t sk[KTOP];        // 16 KB
  __shared__ uint64_t side[SIDECAP];   // 16 KB
  __shared__ uint32_t hist[NB];        // 32 KB (histA copy; reused as class bitmap)
  __shared__ uint32_t sh_dA, ncolM, ncolS;
  int b = blockIdx.x, tid = threadIdx.x, lane = tid & 63;
  const uint32_t* swb = sw + (size_t)b * NDET;
  const uint8_t* clb = cls8 + (size_t)b * NDET;
  const uint32_t* ha = histA + (size_t)b * NB;
  for (int i = tid; i < NB; i += 1024) hist[i] = ha[i];
  if (tid == 0) { ncolM = 0; ncolS = 0; }
  if (tid < 64) keepbm[b * 64 + tid] = 0;
  __syncthreads();

  // ---- wave-parallel FIND: dA = bin containing the 2048th smallest ----
  if (tid < 64) {
    uint32_t segsum = 0;
    for (int i = 0; i < NB / 64; ++i) segsum += hist[lane * (NB / 64) + i];
    uint32_t scan = segsum;
    for (int d = 1; d < 64; d <<= 1) { uint32_t v = __shfl_up(scan, d); if (lane >= d) scan += v; }
    uint32_t excl = scan - segsum;
    bool win = (excl < KTOP) && (KTOP <= scan);
    uint64_t wb = __ballot(win);
    int S = __ffsll((unsigned long long)wb) - 1;
    uint32_t kRem = KTOP - __shfl(excl, S);
    uint32_t v0 = hist[S * (NB / 64) + lane];
    uint32_t v1 = hist[S * (NB / 64) + 64 + lane];
    uint32_t s0 = v0;
    for (int d = 1; d < 64; d <<= 1) { uint32_t v = __shfl_up(s0, d); if (lane >= d) s0 += v; }
    uint32_t tot0 = __shfl(s0, 63);
    uint32_t e0 = s0 - v0;
    uint32_t s1 = v1;
    for (int d = 1; d < 64; d <<= 1) { uint32_t v = __shfl_up(s1, d); if (lane >= d) s1 += v; }
    uint32_t e1 = s1 - v1 + tot0;
    bool w0 = (e0 < kRem) && (kRem <= e0 + v0);
    bool w1 = (e1 < kRem) && (kRem <= e1 + v1);
    uint64_t b0m = __ballot(w0), b1m = __ballot(w1);
    int dA;
    if (b0m) dA = S * (NB / 64) + (__ffsll((unsigned long long)b0m) - 1);
    else     dA = S * (NB / 64) + 64 + (__ffsll((unsigned long long)b1m) - 1);
    if (lane == 0) sh_dA = (uint32_t)dA;
  }
  __syncthreads();
  uint32_t dA = sh_dA;

  // ---- ONE combined scan: append main (bin<dA) to sk, side (bin==dA) ----
  for (int n = tid; n < NDET; n += 1024) {
    uint32_t hi = swb[n];
    uint32_t bin = (hi != INVHI) ? ((hi - 0x40000000u) >> 13) : (NB - 1);
    bool mp = (bin < dA);
    bool sp = (bin == dA);
    uint64_t bm_ = __ballot(mp);
    uint64_t bs_ = __ballot(sp);
    uint32_t baseM = 0, baseS = 0;
    if (lane == 0) {
      if (bm_) baseM = atomicAdd(&ncolM, (uint32_t)__popcll(bm_));
      if (bs_) baseS = atomicAdd(&ncolS, (uint32_t)__popcll(bs_));
    }
    baseM = __shfl(baseM, 0);
    baseS = __shfl(baseS, 0);
    uint64_t lmask = (1ull << lane) - 1ull;
    if (mp) {
      uint64_t key = ((uint64_t)hi << 32) | (((uint32_t)n << 7) | clb[n]);
      sk[baseM + (uint32_t)__popcll(bm_ & lmask)] = key;
    }
    if (sp) {
      uint64_t key = ((uint64_t)hi << 32) | (((uint32_t)n << 7) | clb[n]);
      uint32_t p = baseS + (uint32_t)__popcll(bs_ & lmask);
      if (p < SIDECAP) side[p] = key;
    }
  }
  __syncthreads();

  // ---- side ranking: the (2048-C) smallest side keys fill sk[C..2048) ----
  {
    uint32_t C = ncolM;
    uint32_t s = ncolS; if (s > SIDECAP) s = SIDECAP;
    uint32_t rp = KTOP - C;
    for (uint32_t i = tid; i < s; i += 1024) {
      uint64_t ki = side[i];
      uint32_t rk = 0;
      for (uint32_t j = 0; j < s; ++j) rk += (side[j] < ki) ? 1u : 0u;
      if (rk < rp) sk[C + rk] = ki;
    }
  }
  __syncthreads();

  // ---- hybrid register/LDS bitonic sort (ascending; keys distinct) ----
  {
    int wv = tid >> 6, ln = tid & 63;
    int i1 = wv * 128 + ln;
    int i2 = i1 + 64;
    uint64_t lo = sk[i1], hi = sk[i2];

#define CMPEX_SHFL(j, kk) { \
      uint64_t plo = __shfl_xor((unsigned long long)lo, (j)); \
      uint64_t phi = __shfl_xor((unsigned long long)hi, (j)); \
      bool low1 = ((ln & (j)) == 0); \
      bool km1 = (low1 == ((i1 & (kk)) == 0)); \
      lo = km1 ? (lo < plo ? lo : plo) : (lo > plo ? lo : plo); \
      bool km2 = (low1 == ((i2 & (kk)) == 0)); \
      hi = km2 ? (hi < phi ? hi : phi) : (hi > phi ? hi : phi); }
#define CMPEX_LANE(kk) { \
      bool asc_ = ((i1 & (kk)) == 0); \
      uint64_t mn = lo < hi ? lo : hi; \
      uint64_t mx = lo < hi ? hi : lo; \
      lo = asc_ ? mn : mx; hi = asc_ ? mx : mn; }

    for (int kk = 2; kk <= 128; kk <<= 1) {
      for (int j = kk >> 1; j > 0; j >>= 1) {
        if (j == 64) { CMPEX_LANE(kk) }
        else CMPEX_SHFL(j, kk)
      }
    }
    for (int kk = 256; kk <= KTOP; kk <<= 1) {
      for (int j = kk >> 1; j >= 128; j >>= 1) {
        sk[i1] = lo; sk[i2] = hi;
        __syncthreads();
        uint64_t p1 = sk[i1 ^ j], p2 = sk[i2 ^ j];
        bool km1 = (((i1 & j) == 0) == ((i1 & kk) == 0));
        lo = km1 ? (lo < p1 ? lo : p1) : (lo > p1 ? lo : p1);
        bool km2 = (((i2 & j) == 0) == ((i2 & kk) == 0));
        hi = km2 ? (hi < p2 ? hi : p2) : (hi > p2 ? hi : p2);
        __syncthreads();
      }
      for (int j = 64; j > 0; j >>= 1) {
        if (j == 64) { CMPEX_LANE(kk) }
        else CMPEX_SHFL(j, kk)
      }
    }
    sk[i1] = lo; sk[i2] = hi;
  }
  __syncthreads();

  // ---- class bitmap (reuse hist space; BMW=5120 <= NB) ----
  uint32_t* bm = hist;
  for (int i = tid; i < BMW; i += 1024) bm[i] = 0;
  __syncthreads();

  // ---- derive arrays ----
  for (int rr = tid; rr < KTOP; rr += 1024) {
    uint64_t key = sk[rr];
    float score = unmono_f32(~(uint32_t)(key >> 32));
    uint32_t low = (uint32_t)key;
    uint32_t n = low >> 7;
    uint32_t cls = low & 127u;
    if (score > 0.0f) atomicOr(&bm[cls * 64 + (rr >> 5)], 1u << (rr & 31));
    const float* p = pred + ((size_t)b * NDET + n) * PREDC;
    float x = p[0], y = p[1], w = p[2], h = p[3];
    float hw = __fmul_rn(w, 0.5f), hh = __fmul_rn(h, 0.5f);
    float x1 = __fsub_rn(x, hw), y1 = __fsub_rn(y, hh);
    float x2 = __fadd_rn(x, hw), y2 = __fadd_rn(y, hh);
    float clsf = (float)cls;
    float off = __fmul_rn(clsf, MAXWH);
    size_t o = (size_t)b * KTOP + rr;
    s_n[o] = n;
    s_score[o] = score;
    s_clsf[o] = clsf;
    s_box[o * 4 + 0] = x1; s_box[o * 4 + 1] = y1;
    s_box[o * 4 + 2] = x2; s_box[o * 4 + 3] = y2;
    s_obox[o * 4 + 0] = __fadd_rn(x1, off); s_obox[o * 4 + 1] = __fadd_rn(y1, off);
    s_obox[o * 4 + 2] = __fadd_rn(x2, off); s_obox[o * 4 + 3] = __fadd_rn(y2, off);
  }
  __syncthreads();
  for (int i = tid; i < BMW; i += 1024) clsbm[(size_t)b * BMW + i] = bm[i];
}

// K3: per-(batch,class) greedy NMS (exact decomposition: cross-class IoU == 0).
__global__ void __launch_bounds__(64) k_cnms(
    const uint32_t* __restrict__ clsbm, const float* __restrict__ s_obox,
    uint32_t* __restrict__ keepbm) {
  __shared__ uint16_t memb[KTOP];                 // 4 KB
  __shared__ float bx1[KTOP], by1[KTOP], bx2[KTOP], by2[KTOP];  // 32 KB
  __shared__ uint64_t aliveM[KTOP / 64];
  int b = blockIdx.x / NCLS, c = blockIdx.x % NCLS;
  int lane = threadIdx.x;
  uint32_t w = clsbm[(size_t)b * BMW + c * 64 + lane];
  int cnt = __popc(w);
  int scan = cnt;
  for (int d = 1; d < 64; d <<= 1) {
    int v = __shfl_up(scan, d);
    if (lane >= d) scan += v;
  }
  int m = __shfl(scan, 63);
  if (m == 0) return;
  int p = scan - cnt;
  uint32_t ww = w;
  while (ww) { int t = __ffs(ww) - 1; ww &= ww - 1; memb[p++] = (uint16_t)(lane * 32 + t); }
  __syncthreads();
  for (int i = lane; i < m; i += 64) {
    const float* bp = s_obox + ((size_t)b * KTOP + memb[i]) * 4;
    bx1[i] = bp[0]; by1[i] = bp[1]; bx2[i] = bp[2]; by2[i] = bp[3];
  }
  __syncthreads();
  int nch = (m + 63) >> 6;
  for (int ch = 0; ch < nch; ++ch) {
    int base = ch * 64;
    int my = base + lane;
    bool has = my < m;
    float ax1 = 0, ay1 = 0, ax2 = 0, ay2 = 0, aarea = 0;
    if (has) {
      ax1 = bx1[my]; ay1 = by1[my]; ax2 = bx2[my]; ay2 = by2[my];
      aarea = __fmul_rn(__fsub_rn(ax2, ax1), __fsub_rn(ay2, ay1));
    }
    bool supp = false;
#define IOU_SUPP(j, guard) { \
      float jx1 = bx1[j], jy1 = by1[j], jx2 = bx2[j], jy2 = by2[j]; \
      float jarea = __fmul_rn(__fsub_rn(jx2, jx1), __fsub_rn(jy2, jy1)); \
      float ltx = fmaxf(jx1, ax1), lty = fmaxf(jy1, ay1); \
      float rbx = fminf(jx2, ax2), rby = fminf(jy2, ay2); \
      float wx = fmaxf(__fsub_rn(rbx, ltx), 0.0f); \
      float wy = fmaxf(__fsub_rn(rby, lty), 0.0f); \
      float inter = __fmul_rn(wx, wy); \
      float denom = __fadd_rn(__fsub_rn(__fadd_rn(jarea, aarea), inter), 1e-7f); \
      float iou = __fdiv_rn(inter, denom); \
      supp = supp || ((guard) && iou > IOU_THR); }
    for (int pc = 0; pc < ch; ++pc) {
      uint64_t aw = aliveM[pc];
      while (aw) {
        int e = __ffsll((unsigned long long)aw) - 1; aw &= aw - 1;
        int j = pc * 64 + e;
        IOU_SUPP(j, has)
      }
    }
    uint64_t sm = __ballot(supp);
    int csz = (m - base >= 64) ? 64 : (m - base);
    for (int d = 0; d < csz; ++d) {
      if (!((sm >> d) & 1ull)) {
        int j = base + d;
        IOU_SUPP(j, (lane > d) && has)
        sm = __ballot(supp);
      }
    }
    uint64_t vmask = (csz == 64) ? ~0ull : ((1ull << csz) - 1ull);
    if (lane == 0) aliveM[ch] = (~sm) & vmask;
    __syncthreads();
    if (has && !supp) {
      int rk = memb[my];
      atomicOr(&keepbm[b * 64 + (rk >> 5)], 1u << (rk & 31));
    }
  }
}

// K4: gather + DIRECT write to d_out. Per-batch blocks; slot->rank table
// rebuilt in LDS from keepbm. 16B nontemporal stores, max outstanding writes.
__global__ void __launch_bounds__(256) k_outw(
    const uint32_t* __restrict__ keepbm, const uint32_t* __restrict__ s_n,
    const float* __restrict__ s_score, const float* __restrict__ s_clsf,
    const float* __restrict__ s_box, const float* __restrict__ logits,
    fx4* __restrict__ dout) {
  __shared__ int src[MAXDET];
  int b = blockIdx.x / BPB;
  int jb = blockIdx.x % BPB;
  int tid = threadIdx.x;
  for (int s = tid; s < MAXDET; s += 256) src[s] = -1;
  __syncthreads();
  if (tid < 64) {
    uint32_t keep = keepbm[b * 64 + tid];
    uint32_t cnt = __popc(keep);
    uint32_t scan = cnt;
    for (int d = 1; d < 64; d <<= 1) {
      uint32_t v = __shfl_up(scan, d);
      if (tid >= d) scan += v;
    }
    uint32_t pfx = scan - cnt;
    int lo = tid * 32;
    while (keep) {
      int t = __ffs(keep) - 1;
      keep &= keep - 1;
      if (pfx < MAXDET) src[pfx] = lo + t;
      ++pfx;
    }
  }
  __syncthreads();
  int i = jb * 256 + tid;          // quad index within batch
  if (i >= QPB) return;
  float v0, v1, v2, v3;
#define GETV(k, dst) { \
    int idx = i * 4 + k; \
    int slot = idx / OUTC; \
    int c = idx - slot * OUTC; \
    int r = src[slot]; \
    float x = 0.0f; \
    if (r >= 0) { \
      size_t o = (size_t)b * KTOP + r; \
      if (c < 4) x = s_box[o * 4 + c]; \
      else if (c == 4) x = s_score[o]; \
      else if (c == 5) x = s_clsf[o]; \
      else x = logits[((size_t)b * NDET + s_n[o]) * NCLS + (c - 6)]; \
    } \
    dst = x; }
  GETV(0, v0) GETV(1, v1) GETV(2, v2) GETV(3, v3)
  fx4 f4 = {v0, v1, v2, v3};
  __builtin_nontemporal_store(f4, &dout[(size_t)b * QPB + i]);
}

extern "C" void kernel_launch(void* const* d_in, const int* in_sizes, int n_in,
                              void* d_out, int out_size, void* d_ws, size_t ws_size,
                              hipStream_t stream) {
  const float* pred = (const float*)d_in[0];
  const float* logits = (const float*)d_in[1];

  char* ws = (char*)d_ws;
  size_t off = 0;
  auto alloc = [&](size_t bytes) -> void* {
    void* p = ws + off;
    off += (bytes + 255) & ~(size_t)255;
    return p;
  };
  uint32_t* sw    = (uint32_t*)alloc((size_t)BATCH * NDET * 4);
  uint8_t*  cls8  = (uint8_t*)alloc((size_t)BATCH * NDET);
  uint32_t* histA = (uint32_t*)alloc((size_t)BATCH * NB * 4);
  uint32_t* s_n   = (uint32_t*)alloc((size_t)BATCH * KTOP * 4);
  float*    s_sc  = (float*)alloc((size_t)BATCH * KTOP * 4);
  float*    s_cl  = (float*)alloc((size_t)BATCH * KTOP * 4);
  uint32_t* clsbm = (uint32_t*)alloc((size_t)BATCH * BMW * 4);
  float*    s_box = (float*)alloc((size_t)BATCH * KTOP * 16);
  float*    s_ob  = (float*)alloc((size_t)BATCH * KTOP * 16);
  uint32_t* keepb = (uint32_t*)alloc((size_t)BATCH * 64 * 4);
  (void)ws_size; (void)in_sizes; (void)n_in;

  hipMemsetAsync(histA, 0, (size_t)BATCH * NB * 4, stream);
  k_keys<<<(BATCH * NDET) / 64, 256, 0, stream>>>(pred, sw, cls8, histA);
  k_sel<<<BATCH, 1024, 0, stream>>>(sw, cls8, pred, histA, s_n, s_sc, s_cl, clsbm, s_box, s_ob, keepb);
  k_cnms<<<BATCH * NCLS, 64, 0, stream>>>(clsbm, s_ob, keepb);
  k_outw<<<BATCH * BPB, 256, 0, stream>>>(keepb, s_n, s_sc, s_cl, s_box, logits, (fx4*)d_out);
}

// Round 18
// 130.687 us; speedup vs baseline: 1.0001x; 1.0001x over previous
//
#include <hip/hip_runtime.h>
#include <stdint.h>

#define BATCH 16
#define NDET 25200
#define NCLS 80
#define PREDC 85
#define KTOP 2048
#define MAXDET 300
#define OUTC 86
#define CONF_THR 0.4f
#define IOU_THR 0.45f
#define MAXWH 4096.0f
#define INVHI 0xBF800000u       // ~mono(-1.0f): score word of invalid rows
#define BMW (NCLS * 64)         // class bitmap words per batch (80 classes x 64)
#define NB 8192                 // histogram bins (13 bits of hi-0x40000000)
#define SIDECAP 2048
#define QPB ((MAXDET * OUTC) / 4)   // 6450 float4 per batch
#define BPB ((QPB + 255) / 256)     // 26 blocks per batch

typedef float fx4 __attribute__((ext_vector_type(4)));

// ---- monotone float<->uint mapping (ascending) ----
__device__ __forceinline__ uint32_t mono_f32(float f) {
  uint32_t u = __float_as_uint(f);
  return (u & 0x80000000u) ? ~u : (u | 0x80000000u);
}
__device__ __forceinline__ float unmono_f32(uint32_t m) {
  uint32_t u = (m & 0x80000000u) ? (m & 0x7FFFFFFFu) : ~m;
  return __uint_as_float(u);
}

// K0: zero histA. Round-17 lesson: hipMemsetAsync's rocclr fill kernel costs
// ~78us in the timed graph REGARDLESS of size — zero via own kernel (~3us).
__global__ void k_zero(fx4* __restrict__ p) {
  fx4 z = {0.f, 0.f, 0.f, 0.f};
  p[blockIdx.x * 256 + threadIdx.x] = z;
}

// K1: obj-gated score/argmax + fused pass-A histogram.
__global__ void __launch_bounds__(256) k_keys(const float* __restrict__ pred,
                                              uint32_t* __restrict__ sw,
                                              uint8_t* __restrict__ cls8,
                                              uint32_t* __restrict__ histA) {
  __shared__ uint32_t invc[2];
  if (threadIdx.x < 2) invc[threadIdx.x] = 0;
  __syncthreads();
  int gq = blockIdx.x * 64 + (threadIdx.x >> 2);   // 64 rows per block
  int q = threadIdx.x & 3;
  const float* row = pred + (size_t)gq * PREDC;
  float obj = row[4];
  float score = -1.0f;
  uint32_t cl = 0;
  if (obj > CONF_THR) {
    float best = -1e30f;
    int bc = 0;
#pragma unroll
    for (int k = 0; k < 5; ++k) {
#pragma unroll
      for (int j = 0; j < 4; ++j) {
        int c = k * 16 + q * 4 + j;                 // ascending within lane
        float s = __fmul_rn(row[5 + c], obj);       // single-rounded, no contraction
        if (s > best) { best = s; bc = c; }         // strict > : first max
      }
    }
    for (int d = 1; d <= 2; d <<= 1) {              // quad reduce
      float vo = __shfl_xor(best, d);
      int co = __shfl_xor(bc, d);
      if (vo > best || (vo == best && co < bc)) { best = vo; bc = co; }
    }
    if (best > CONF_THR) { score = best; cl = (uint32_t)bc; }
  }
  int b = gq / NDET;
  int b0 = (blockIdx.x * 64) / NDET;
  if (q == 0) {
    uint32_t hi = ~mono_f32(score);
    sw[gq] = hi;
    cls8[gq] = (uint8_t)cl;
    if (score > 0.0f)
      atomicAdd(&histA[(size_t)b * NB + ((hi - 0x40000000u) >> 13)], 1u);
    else
      atomicAdd(&invc[b - b0], 1u);
  }
  __syncthreads();
  if (threadIdx.x < 2) {
    uint32_t c = invc[threadIdx.x];
    if (c) atomicAdd(&histA[(size_t)(b0 + threadIdx.x) * NB + (NB - 1)], c);
  }
}

// K2: wave-parallel FIND on precomputed histA + ONE combined scan
// (main append bin<dA, side list bin==dA) + O(s^2) full-key side ranking +
// hybrid register/LDS bitonic sort + derive (+ class bitmap).
__global__ void __launch_bounds__(1024) k_sel(
    const uint32_t* __restrict__ sw, const uint8_t* __restrict__ cls8,
    const float* __restrict__ pred, const uint32_t* __restrict__ histA,
    uint32_t* __restrict__ s_n, float* __restrict__ s_score, float* __restrict__ s_clsf,
    uint32_t* __restrict__ clsbm, float* __restrict__ s_box, float* __restrict__ s_obox,
    uint32_t* __restrict__ keepbm) {
  __shared__ uint64_t sk[KTOP];        // 16 KB
  __shared__ uint64_t side[SIDECAP];   // 16 KB
  __shared__ uint32_t hist[NB];        // 32 KB (histA copy; reused as class bitmap)
  __shared__ uint32_t sh_dA, ncolM, ncolS;
  int b = blockIdx.x, tid = threadIdx.x, lane = tid & 63;
  const uint32_t* swb = sw + (size_t)b * NDET;
  const uint8_t* clb = cls8 + (size_t)b * NDET;
  const uint32_t* ha = histA + (size_t)b * NB;
  for (int i = tid; i < NB; i += 1024) hist[i] = ha[i];
  if (tid == 0) { ncolM = 0; ncolS = 0; }
  if (tid < 64) keepbm[b * 64 + tid] = 0;
  __syncthreads();

  // ---- wave-parallel FIND: dA = bin containing the 2048th smallest ----
  if (tid < 64) {
    uint32_t segsum = 0;
    for (int i = 0; i < NB / 64; ++i) segsum += hist[lane * (NB / 64) + i];
    uint32_t scan = segsum;
    for (int d = 1; d < 64; d <<= 1) { uint32_t v = __shfl_up(scan, d); if (lane >= d) scan += v; }
    uint32_t excl = scan - segsum;
    bool win = (excl < KTOP) && (KTOP <= scan);
    uint64_t wb = __ballot(win);
    int S = __ffsll((unsigned long long)wb) - 1;
    uint32_t kRem = KTOP - __shfl(excl, S);
    uint32_t v0 = hist[S * (NB / 64) + lane];
    uint32_t v1 = hist[S * (NB / 64) + 64 + lane];
    uint32_t s0 = v0;
    for (int d = 1; d < 64; d <<= 1) { uint32_t v = __shfl_up(s0, d); if (lane >= d) s0 += v; }
    uint32_t tot0 = __shfl(s0, 63);
    uint32_t e0 = s0 - v0;
    uint32_t s1 = v1;
    for (int d = 1; d < 64; d <<= 1) { uint32_t v = __shfl_up(s1, d); if (lane >= d) s1 += v; }
    uint32_t e1 = s1 - v1 + tot0;
    bool w0 = (e0 < kRem) && (kRem <= e0 + v0);
    bool w1 = (e1 < kRem) && (kRem <= e1 + v1);
    uint64_t b0m = __ballot(w0), b1m = __ballot(w1);
    int dA;
    if (b0m) dA = S * (NB / 64) + (__ffsll((unsigned long long)b0m) - 1);
    else     dA = S * (NB / 64) + 64 + (__ffsll((unsigned long long)b1m) - 1);
    if (lane == 0) sh_dA = (uint32_t)dA;
  }
  __syncthreads();
  uint32_t dA = sh_dA;

  // ---- ONE combined scan: append main (bin<dA) to sk, side (bin==dA) ----
  for (int n = tid; n < NDET; n += 1024) {
    uint32_t hi = swb[n];
    uint32_t bin = (hi != INVHI) ? ((hi - 0x40000000u) >> 13) : (NB - 1);
    bool mp = (bin < dA);
    bool sp = (bin == dA);
    uint64_t bm_ = __ballot(mp);
    uint64_t bs_ = __ballot(sp);
    uint32_t baseM = 0, baseS = 0;
    if (lane == 0) {
      if (bm_) baseM = atomicAdd(&ncolM, (uint32_t)__popcll(bm_));
      if (bs_) baseS = atomicAdd(&ncolS, (uint32_t)__popcll(bs_));
    }
    baseM = __shfl(baseM, 0);
    baseS = __shfl(baseS, 0);
    uint64_t lmask = (1ull << lane) - 1ull;
    if (mp) {
      uint64_t key = ((uint64_t)hi << 32) | (((uint32_t)n << 7) | clb[n]);
      sk[baseM + (uint32_t)__popcll(bm_ & lmask)] = key;
    }
    if (sp) {
      uint64_t key = ((uint64_t)hi << 32) | (((uint32_t)n << 7) | clb[n]);
      uint32_t p = baseS + (uint32_t)__popcll(bs_ & lmask);
      if (p < SIDECAP) side[p] = key;
    }
  }
  __syncthreads();

  // ---- side ranking: the (2048-C) smallest side keys fill sk[C..2048) ----
  {
    uint32_t C = ncolM;
    uint32_t s = ncolS; if (s > SIDECAP) s = SIDECAP;
    uint32_t rp = KTOP - C;
    for (uint32_t i = tid; i < s; i += 1024) {
      uint64_t ki = side[i];
      uint32_t rk = 0;
      for (uint32_t j = 0; j < s; ++j) rk += (side[j] < ki) ? 1u : 0u;
      if (rk < rp) sk[C + rk] = ki;
    }
  }
  __syncthreads();

  // ---- hybrid register/LDS bitonic sort (ascending; keys distinct) ----
  {
    int wv = tid >> 6, ln = tid & 63;
    int i1 = wv * 128 + ln;
    int i2 = i1 + 64;
    uint64_t lo = sk[i1], hi = sk[i2];

#define CMPEX_SHFL(j, kk) { \
      uint64_t plo = __shfl_xor((unsigned long long)lo, (j)); \
      uint64_t phi = __shfl_xor((unsigned long long)hi, (j)); \
      bool low1 = ((ln & (j)) == 0); \
      bool km1 = (low1 == ((i1 & (kk)) == 0)); \
      lo = km1 ? (lo < plo ? lo : plo) : (lo > plo ? lo : plo); \
      bool km2 = (low1 == ((i2 & (kk)) == 0)); \
      hi = km2 ? (hi < phi ? hi : phi) : (hi > phi ? hi : phi); }
#define CMPEX_LANE(kk) { \
      bool asc_ = ((i1 & (kk)) == 0); \
      uint64_t mn = lo < hi ? lo : hi; \
      uint64_t mx = lo < hi ? hi : lo; \
      lo = asc_ ? mn : mx; hi = asc_ ? mx : mn; }

    for (int kk = 2; kk <= 128; kk <<= 1) {
      for (int j = kk >> 1; j > 0; j >>= 1) {
        if (j == 64) { CMPEX_LANE(kk) }
        else CMPEX_SHFL(j, kk)
      }
    }
    for (int kk = 256; kk <= KTOP; kk <<= 1) {
      for (int j = kk >> 1; j >= 128; j >>= 1) {
        sk[i1] = lo; sk[i2] = hi;
        __syncthreads();
        uint64_t p1 = sk[i1 ^ j], p2 = sk[i2 ^ j];
        bool km1 = (((i1 & j) == 0) == ((i1 & kk) == 0));
        lo = km1 ? (lo < p1 ? lo : p1) : (lo > p1 ? lo : p1);
        bool km2 = (((i2 & j) == 0) == ((i2 & kk) == 0));
        hi = km2 ? (hi < p2 ? hi : p2) : (hi > p2 ? hi : p2);
        __syncthreads();
      }
      for (int j = 64; j > 0; j >>= 1) {
        if (j == 64) { CMPEX_LANE(kk) }
        else CMPEX_SHFL(j, kk)
      }
    }
    sk[i1] = lo; sk[i2] = hi;
  }
  __syncthreads();

  // ---- class bitmap (reuse hist space; BMW=5120 <= NB) ----
  uint32_t* bm = hist;
  for (int i = tid; i < BMW; i += 1024) bm[i] = 0;
  __syncthreads();

  // ---- derive arrays ----
  for (int rr = tid; rr < KTOP; rr += 1024) {
    uint64_t key = sk[rr];
    float score = unmono_f32(~(uint32_t)(key >> 32));
    uint32_t low = (uint32_t)key;
    uint32_t n = low >> 7;
    uint32_t cls = low & 127u;
    if (score > 0.0f) atomicOr(&bm[cls * 64 + (rr >> 5)], 1u << (rr & 31));
    const float* p = pred + ((size_t)b * NDET + n) * PREDC;
    float x = p[0], y = p[1], w = p[2], h = p[3];
    float hw = __fmul_rn(w, 0.5f), hh = __fmul_rn(h, 0.5f);
    float x1 = __fsub_rn(x, hw), y1 = __fsub_rn(y, hh);
    float x2 = __fadd_rn(x, hw), y2 = __fadd_rn(y, hh);
    float clsf = (float)cls;
    float off = __fmul_rn(clsf, MAXWH);
    size_t o = (size_t)b * KTOP + rr;
    s_n[o] = n;
    s_score[o] = score;
    s_clsf[o] = clsf;
    s_box[o * 4 + 0] = x1; s_box[o * 4 + 1] = y1;
    s_box[o * 4 + 2] = x2; s_box[o * 4 + 3] = y2;
    s_obox[o * 4 + 0] = __fadd_rn(x1, off); s_obox[o * 4 + 1] = __fadd_rn(y1, off);
    s_obox[o * 4 + 2] = __fadd_rn(x2, off); s_obox[o * 4 + 3] = __fadd_rn(y2, off);
  }
  __syncthreads();
  for (int i = tid; i < BMW; i += 1024) clsbm[(size_t)b * BMW + i] = bm[i];
}

// K3: per-(batch,class) greedy NMS (exact decomposition: cross-class IoU == 0).
__global__ void __launch_bounds__(64) k_cnms(
    const uint32_t* __restrict__ clsbm, const float* __restrict__ s_obox,
    uint32_t* __restrict__ keepbm) {
  __shared__ uint16_t memb[KTOP];                 // 4 KB
  __shared__ float bx1[KTOP], by1[KTOP], bx2[KTOP], by2[KTOP];  // 32 KB
  __shared__ uint64_t aliveM[KTOP / 64];
  int b = blockIdx.x / NCLS, c = blockIdx.x % NCLS;
  int lane = threadIdx.x;
  uint32_t w = clsbm[(size_t)b * BMW + c * 64 + lane];
  int cnt = __popc(w);
  int scan = cnt;
  for (int d = 1; d < 64; d <<= 1) {
    int v = __shfl_up(scan, d);
    if (lane >= d) scan += v;
  }
  int m = __shfl(scan, 63);
  if (m == 0) return;
  int p = scan - cnt;
  uint32_t ww = w;
  while (ww) { int t = __ffs(ww) - 1; ww &= ww - 1; memb[p++] = (uint16_t)(lane * 32 + t); }
  __syncthreads();
  for (int i = lane; i < m; i += 64) {
    const float* bp = s_obox + ((size_t)b * KTOP + memb[i]) * 4;
    bx1[i] = bp[0]; by1[i] = bp[1]; bx2[i] = bp[2]; by2[i] = bp[3];
  }
  __syncthreads();
  int nch = (m + 63) >> 6;
  for (int ch = 0; ch < nch; ++ch) {
    int base = ch * 64;
    int my = base + lane;
    bool has = my < m;
    float ax1 = 0, ay1 = 0, ax2 = 0, ay2 = 0, aarea = 0;
    if (has) {
      ax1 = bx1[my]; ay1 = by1[my]; ax2 = bx2[my]; ay2 = by2[my];
      aarea = __fmul_rn(__fsub_rn(ax2, ax1), __fsub_rn(ay2, ay1));
    }
    bool supp = false;
#define IOU_SUPP(j, guard) { \
      float jx1 = bx1[j], jy1 = by1[j], jx2 = bx2[j], jy2 = by2[j]; \
      float jarea = __fmul_rn(__fsub_rn(jx2, jx1), __fsub_rn(jy2, jy1)); \
      float ltx = fmaxf(jx1, ax1), lty = fmaxf(jy1, ay1); \
      float rbx = fminf(jx2, ax2), rby = fminf(jy2, ay2); \
      float wx = fmaxf(__fsub_rn(rbx, ltx), 0.0f); \
      float wy = fmaxf(__fsub_rn(rby, lty), 0.0f); \
      float inter = __fmul_rn(wx, wy); \
      float denom = __fadd_rn(__fsub_rn(__fadd_rn(jarea, aarea), inter), 1e-7f); \
      float iou = __fdiv_rn(inter, denom); \
      supp = supp || ((guard) && iou > IOU_THR); }
    for (int pc = 0; pc < ch; ++pc) {
      uint64_t aw = aliveM[pc];
      while (aw) {
        int e = __ffsll((unsigned long long)aw) - 1; aw &= aw - 1;
        int j = pc * 64 + e;
        IOU_SUPP(j, has)
      }
    }
    uint64_t sm = __ballot(supp);
    int csz = (m - base >= 64) ? 64 : (m - base);
    for (int d = 0; d < csz; ++d) {
      if (!((sm >> d) & 1ull)) {
        int j = base + d;
        IOU_SUPP(j, (lane > d) && has)
        sm = __ballot(supp);
      }
    }
    uint64_t vmask = (csz == 64) ? ~0ull : ((1ull << csz) - 1ull);
    if (lane == 0) aliveM[ch] = (~sm) & vmask;
    __syncthreads();
    if (has && !supp) {
      int rk = memb[my];
      atomicOr(&keepbm[b * 64 + (rk >> 5)], 1u << (rk & 31));
    }
  }
}

// K4: gather + DIRECT write to d_out. Per-batch blocks; slot->rank table
// rebuilt in LDS from keepbm. 16B nontemporal stores, max outstanding writes.
__global__ void __launch_bounds__(256) k_outw(
    const uint32_t* __restrict__ keepbm, const uint32_t* __restrict__ s_n,
    const float* __restrict__ s_score, const float* __restrict__ s_clsf,
    const float* __restrict__ s_box, const float* __restrict__ logits,
    fx4* __restrict__ dout) {
  __shared__ int src[MAXDET];
  int b = blockIdx.x / BPB;
  int jb = blockIdx.x % BPB;
  int tid = threadIdx.x;
  for (int s = tid; s < MAXDET; s += 256) src[s] = -1;
  __syncthreads();
  if (tid < 64) {
    uint32_t keep = keepbm[b * 64 + tid];
    uint32_t cnt = __popc(keep);
    uint32_t scan = cnt;
    for (int d = 1; d < 64; d <<= 1) {
      uint32_t v = __shfl_up(scan, d);
      if (tid >= d) scan += v;
    }
    uint32_t pfx = scan - cnt;
    int lo = tid * 32;
    while (keep) {
      int t = __ffs(keep) - 1;
      keep &= keep - 1;
      if (pfx < MAXDET) src[pfx] = lo + t;
      ++pfx;
    }
  }
  __syncthreads();
  int i = jb * 256 + tid;          // quad index within batch
  if (i >= QPB) return;
  float v0, v1, v2, v3;
#define GETV(k, dst) { \
    int idx = i * 4 + k; \
    int slot = idx / OUTC; \
    int c = idx - slot * OUTC; \
    int r = src[slot]; \
    float x = 0.0f; \
    if (r >= 0) { \
      size_t o = (size_t)b * KTOP + r; \
      if (c < 4) x = s_box[o * 4 + c]; \
      else if (c == 4) x = s_score[o]; \
      else if (c == 5) x = s_clsf[o]; \
      else x = logits[((size_t)b * NDET + s_n[o]) * NCLS + (c - 6)]; \
    } \
    dst = x; }
  GETV(0, v0) GETV(1, v1) GETV(2, v2) GETV(3, v3)
  fx4 f4 = {v0, v1, v2, v3};
  __builtin_nontemporal_store(f4, &dout[(size_t)b * QPB + i]);
}

extern "C" void kernel_launch(void* const* d_in, const int* in_sizes, int n_in,
                              void* d_out, int out_size, void* d_ws, size_t ws_size,
                              hipStream_t stream) {
  const float* pred = (const float*)d_in[0];
  const float* logits = (const float*)d_in[1];

  char* ws = (char*)d_ws;
  size_t off = 0;
  auto alloc = [&](size_t bytes) -> void* {
    void* p = ws + off;
    off += (bytes + 255) & ~(size_t)255;
    return p;
  };
  uint32_t* sw    = (uint32_t*)alloc((size_t)BATCH * NDET * 4);
  uint8_t*  cls8  = (uint8_t*)alloc((size_t)BATCH * NDET);
  uint32_t* histA = (uint32_t*)alloc((size_t)BATCH * NB * 4);
  uint32_t* s_n   = (uint32_t*)alloc((size_t)BATCH * KTOP * 4);
  float*    s_sc  = (float*)alloc((size_t)BATCH * KTOP * 4);
  float*    s_cl  = (float*)alloc((size_t)BATCH * KTOP * 4);
  uint32_t* clsbm = (uint32_t*)alloc((size_t)BATCH * BMW * 4);
  float*    s_box = (float*)alloc((size_t)BATCH * KTOP * 16);
  float*    s_ob  = (float*)alloc((size_t)BATCH * KTOP * 16);
  uint32_t* keepb = (uint32_t*)alloc((size_t)BATCH * 64 * 4);
  (void)ws_size; (void)in_sizes; (void)n_in;

  k_zero<<<(BATCH * NB * 4) / (16 * 256), 256, 0, stream>>>((fx4*)histA);
  k_keys<<<(BATCH * NDET) / 64, 256, 0, stream>>>(pred, sw, cls8, histA);
  k_sel<<<BATCH, 1024, 0, stream>>>(sw, cls8, pred, histA, s_n, s_sc, s_cl, clsbm, s_box, s_ob, keepb);
  k_cnms<<<BATCH * NCLS, 64, 0, stream>>>(clsbm, s_ob, keepb);
  k_outw<<<BATCH * BPB, 256, 0, stream>>>(keepb, s_n, s_sc, s_cl, s_box, logits, (fx4*)d_out);
}

// Round 19
// 89.071 us; speedup vs baseline: 1.4674x; 1.4672x over previous
//
#include <hip/hip_runtime.h>
#include <stdint.h>

#define BATCH 16
#define NDET 25200
#define NCLS 80
#define PREDC 85
#define KTOP 2048
#define MAXDET 300
#define OUTC 86
#define CONF_THR 0.4f
#define IOU_THR 0.45f
#define MAXWH 4096.0f
#define INVHI 0xBF800000u       // ~mono(-1.0f): score word of invalid rows
#define BMW (NCLS * 64)         // class bitmap words per batch (80 classes x 64)
#define NB 8192                 // histogram bins (13 bits of hi-0x40000000)
#define SIDECAP 2048
#define QPB ((MAXDET * OUTC) / 4)   // 6450 float4 per batch
#define BPB ((QPB + 255) / 256)     // 26 blocks per batch

typedef float fx4 __attribute__((ext_vector_type(4)));

// ---- monotone float<->uint mapping (ascending) ----
__device__ __forceinline__ uint32_t mono_f32(float f) {
  uint32_t u = __float_as_uint(f);
  return (u & 0x80000000u) ? ~u : (u | 0x80000000u);
}
__device__ __forceinline__ float unmono_f32(uint32_t m) {
  uint32_t u = (m & 0x80000000u) ? (m & 0x7FFFFFFFu) : ~m;
  return __uint_as_float(u);
}

// K1: obj-gated score/argmax, quad (4 lanes) per row. REVERTED to round-16
// form: rounds 17/18 fused a global-atomic histogram here; k_zero-bisect
// showed the +30us regression was exactly that (cross-XCD atomic RMWs),
// not the memset. Histogram now lives in k_sel as LDS atomics.
__global__ void __launch_bounds__(256) k_keys(const float* __restrict__ pred,
                                              uint32_t* __restrict__ sw,
                                              uint8_t* __restrict__ cls8) {
  int gq = blockIdx.x * 64 + (threadIdx.x >> 2);   // 64 rows per block
  int q = threadIdx.x & 3;
  const float* row = pred + (size_t)gq * PREDC;
  float obj = row[4];
  float score = -1.0f;
  uint32_t cl = 0;
  if (obj > CONF_THR) {
    float best = -1e30f;
    int bc = 0;
#pragma unroll
    for (int k = 0; k < 5; ++k) {
#pragma unroll
      for (int j = 0; j < 4; ++j) {
        int c = k * 16 + q * 4 + j;                 // ascending within lane
        float s = __fmul_rn(row[5 + c], obj);       // single-rounded, no contraction
        if (s > best) { best = s; bc = c; }         // strict > : first max
      }
    }
    for (int d = 1; d <= 2; d <<= 1) {              // quad reduce
      float vo = __shfl_xor(best, d);
      int co = __shfl_xor(bc, d);
      if (vo > best || (vo == best && co < bc)) { best = vo; bc = co; }
    }
    if (best > CONF_THR) { score = best; cl = (uint32_t)bc; }
  }
  if (q == 0) {
    sw[gq] = ~mono_f32(score);
    cls8[gq] = (uint8_t)cl;
  }
}

// K2: self-contained selection: LDS histogram build (1 scan) + wave-parallel
// FIND + ONE combined collect scan + O(s^2) side ranking + hybrid
// register/LDS bitonic sort + derive (+ class bitmap).
// Valid bins are [1023,2457] (score in (0.4,1]); bin NB-1 is invalid-only.
__global__ void __launch_bounds__(1024) k_sel(
    const uint32_t* __restrict__ sw, const uint8_t* __restrict__ cls8,
    const float* __restrict__ pred,
    uint32_t* __restrict__ s_n, float* __restrict__ s_score, float* __restrict__ s_clsf,
    uint32_t* __restrict__ clsbm, float* __restrict__ s_box, float* __restrict__ s_obox,
    uint32_t* __restrict__ keepbm) {
  __shared__ uint64_t sk[KTOP];        // 16 KB
  __shared__ uint64_t side[SIDECAP];   // 16 KB
  __shared__ uint32_t hist[NB];        // 32 KB (reused as class bitmap)
  __shared__ uint32_t sh_dA, ncolM, ncolS;
  int b = blockIdx.x, tid = threadIdx.x, lane = tid & 63;
  const uint32_t* swb = sw + (size_t)b * NDET;
  const uint8_t* clb = cls8 + (size_t)b * NDET;
  if (tid == 0) { ncolM = 0; ncolS = 0; }
  if (tid < 64) keepbm[b * 64 + tid] = 0;
  for (int i = tid; i < NB; i += 1024) hist[i] = 0;
  __syncthreads();

  // ---- histogram build: one coalesced scan, LDS atomics ----
  {
    uint32_t invcnt = 0;
    for (int n = tid; n < NDET; n += 1024) {
      uint32_t hi = swb[n];
      if (hi != INVHI) atomicAdd(&hist[(hi - 0x40000000u) >> 13], 1u);
      else ++invcnt;
    }
    for (int d = 1; d < 64; d <<= 1) invcnt += __shfl_xor(invcnt, d);
    if (lane == 0 && invcnt) atomicAdd(&hist[NB - 1], invcnt);
  }
  __syncthreads();

  // ---- wave-parallel FIND: dA = bin containing the 2048th smallest ----
  if (tid < 64) {
    uint32_t segsum = 0;
    for (int i = 0; i < NB / 64; ++i) segsum += hist[lane * (NB / 64) + i];
    uint32_t scan = segsum;
    for (int d = 1; d < 64; d <<= 1) { uint32_t v = __shfl_up(scan, d); if (lane >= d) scan += v; }
    uint32_t excl = scan - segsum;
    bool win = (excl < KTOP) && (KTOP <= scan);
    uint64_t wb = __ballot(win);
    int S = __ffsll((unsigned long long)wb) - 1;
    uint32_t kRem = KTOP - __shfl(excl, S);
    uint32_t v0 = hist[S * (NB / 64) + lane];
    uint32_t v1 = hist[S * (NB / 64) + 64 + lane];
    uint32_t s0 = v0;
    for (int d = 1; d < 64; d <<= 1) { uint32_t v = __shfl_up(s0, d); if (lane >= d) s0 += v; }
    uint32_t tot0 = __shfl(s0, 63);
    uint32_t e0 = s0 - v0;
    uint32_t s1 = v1;
    for (int d = 1; d < 64; d <<= 1) { uint32_t v = __shfl_up(s1, d); if (lane >= d) s1 += v; }
    uint32_t e1 = s1 - v1 + tot0;
    bool w0 = (e0 < kRem) && (kRem <= e0 + v0);
    bool w1 = (e1 < kRem) && (kRem <= e1 + v1);
    uint64_t b0m = __ballot(w0), b1m = __ballot(w1);
    int dA;
    if (b0m) dA = S * (NB / 64) + (__ffsll((unsigned long long)b0m) - 1);
    else     dA = S * (NB / 64) + 64 + (__ffsll((unsigned long long)b1m) - 1);
    if (lane == 0) sh_dA = (uint32_t)dA;
  }
  __syncthreads();
  uint32_t dA = sh_dA;

  // ---- ONE combined scan: append main (bin<dA) to sk, side (bin==dA) ----
  for (int n = tid; n < NDET; n += 1024) {
    uint32_t hi = swb[n];
    uint32_t bin = (hi != INVHI) ? ((hi - 0x40000000u) >> 13) : (NB - 1);
    bool mp = (bin < dA);
    bool sp = (bin == dA);
    uint64_t bm_ = __ballot(mp);
    uint64_t bs_ = __ballot(sp);
    uint32_t baseM = 0, baseS = 0;
    if (lane == 0) {
      if (bm_) baseM = atomicAdd(&ncolM, (uint32_t)__popcll(bm_));
      if (bs_) baseS = atomicAdd(&ncolS, (uint32_t)__popcll(bs_));
    }
    baseM = __shfl(baseM, 0);
    baseS = __shfl(baseS, 0);
    uint64_t lmask = (1ull << lane) - 1ull;
    if (mp) {
      uint64_t key = ((uint64_t)hi << 32) | (((uint32_t)n << 7) | clb[n]);
      sk[baseM + (uint32_t)__popcll(bm_ & lmask)] = key;
    }
    if (sp) {
      uint64_t key = ((uint64_t)hi << 32) | (((uint32_t)n << 7) | clb[n]);
      uint32_t p = baseS + (uint32_t)__popcll(bs_ & lmask);
      if (p < SIDECAP) side[p] = key;
    }
  }
  __syncthreads();

  // ---- side ranking: the (2048-C) smallest side keys fill sk[C..2048) ----
  {
    uint32_t C = ncolM;
    uint32_t s = ncolS; if (s > SIDECAP) s = SIDECAP;
    uint32_t rp = KTOP - C;
    for (uint32_t i = tid; i < s; i += 1024) {
      uint64_t ki = side[i];
      uint32_t rk = 0;
      for (uint32_t j = 0; j < s; ++j) rk += (side[j] < ki) ? 1u : 0u;
      if (rk < rp) sk[C + rk] = ki;
    }
  }
  __syncthreads();

  // ---- hybrid register/LDS bitonic sort (ascending; keys distinct) ----
  {
    int wv = tid >> 6, ln = tid & 63;
    int i1 = wv * 128 + ln;
    int i2 = i1 + 64;
    uint64_t lo = sk[i1], hi = sk[i2];

#define CMPEX_SHFL(j, kk) { \
      uint64_t plo = __shfl_xor((unsigned long long)lo, (j)); \
      uint64_t phi = __shfl_xor((unsigned long long)hi, (j)); \
      bool low1 = ((ln & (j)) == 0); \
      bool km1 = (low1 == ((i1 & (kk)) == 0)); \
      lo = km1 ? (lo < plo ? lo : plo) : (lo > plo ? lo : plo); \
      bool km2 = (low1 == ((i2 & (kk)) == 0)); \
      hi = km2 ? (hi < phi ? hi : phi) : (hi > phi ? hi : phi); }
#define CMPEX_LANE(kk) { \
      bool asc_ = ((i1 & (kk)) == 0); \
      uint64_t mn = lo < hi ? lo : hi; \
      uint64_t mx = lo < hi ? hi : lo; \
      lo = asc_ ? mn : mx; hi = asc_ ? mx : mn; }

    for (int kk = 2; kk <= 128; kk <<= 1) {
      for (int j = kk >> 1; j > 0; j >>= 1) {
        if (j == 64) { CMPEX_LANE(kk) }
        else CMPEX_SHFL(j, kk)
      }
    }
    for (int kk = 256; kk <= KTOP; kk <<= 1) {
      for (int j = kk >> 1; j >= 128; j >>= 1) {
        sk[i1] = lo; sk[i2] = hi;
        __syncthreads();
        uint64_t p1 = sk[i1 ^ j], p2 = sk[i2 ^ j];
        bool km1 = (((i1 & j) == 0) == ((i1 & kk) == 0));
        lo = km1 ? (lo < p1 ? lo : p1) : (lo > p1 ? lo : p1);
        bool km2 = (((i2 & j) == 0) == ((i2 & kk) == 0));
        hi = km2 ? (hi < p2 ? hi : p2) : (hi > p2 ? hi : p2);
        __syncthreads();
      }
      for (int j = 64; j > 0; j >>= 1) {
        if (j == 64) { CMPEX_LANE(kk) }
        else CMPEX_SHFL(j, kk)
      }
    }
    sk[i1] = lo; sk[i2] = hi;
  }
  __syncthreads();

  // ---- class bitmap (reuse hist space; BMW=5120 <= NB) ----
  uint32_t* bm = hist;
  for (int i = tid; i < BMW; i += 1024) bm[i] = 0;
  __syncthreads();

  // ---- derive arrays ----
  for (int rr = tid; rr < KTOP; rr += 1024) {
    uint64_t key = sk[rr];
    float score = unmono_f32(~(uint32_t)(key >> 32));
    uint32_t low = (uint32_t)key;
    uint32_t n = low >> 7;
    uint32_t cls = low & 127u;
    if (score > 0.0f) atomicOr(&bm[cls * 64 + (rr >> 5)], 1u << (rr & 31));
    const float* p = pred + ((size_t)b * NDET + n) * PREDC;
    float x = p[0], y = p[1], w = p[2], h = p[3];
    float hw = __fmul_rn(w, 0.5f), hh = __fmul_rn(h, 0.5f);
    float x1 = __fsub_rn(x, hw), y1 = __fsub_rn(y, hh);
    float x2 = __fadd_rn(x, hw), y2 = __fadd_rn(y, hh);
    float clsf = (float)cls;
    float off = __fmul_rn(clsf, MAXWH);
    size_t o = (size_t)b * KTOP + rr;
    s_n[o] = n;
    s_score[o] = score;
    s_clsf[o] = clsf;
    s_box[o * 4 + 0] = x1; s_box[o * 4 + 1] = y1;
    s_box[o * 4 + 2] = x2; s_box[o * 4 + 3] = y2;
    s_obox[o * 4 + 0] = __fadd_rn(x1, off); s_obox[o * 4 + 1] = __fadd_rn(y1, off);
    s_obox[o * 4 + 2] = __fadd_rn(x2, off); s_obox[o * 4 + 3] = __fadd_rn(y2, off);
  }
  __syncthreads();
  for (int i = tid; i < BMW; i += 1024) clsbm[(size_t)b * BMW + i] = bm[i];
}

// K3: per-(batch,class) greedy NMS (exact decomposition: cross-class IoU == 0).
__global__ void __launch_bounds__(64) k_cnms(
    const uint32_t* __restrict__ clsbm, const float* __restrict__ s_obox,
    uint32_t* __restrict__ keepbm) {
  __shared__ uint16_t memb[KTOP];                 // 4 KB
  __shared__ float bx1[KTOP], by1[KTOP], bx2[KTOP], by2[KTOP];  // 32 KB
  __shared__ uint64_t aliveM[KTOP / 64];
  int b = blockIdx.x / NCLS, c = blockIdx.x % NCLS;
  int lane = threadIdx.x;
  uint32_t w = clsbm[(size_t)b * BMW + c * 64 + lane];
  int cnt = __popc(w);
  int scan = cnt;
  for (int d = 1; d < 64; d <<= 1) {
    int v = __shfl_up(scan, d);
    if (lane >= d) scan += v;
  }
  int m = __shfl(scan, 63);
  if (m == 0) return;
  int p = scan - cnt;
  uint32_t ww = w;
  while (ww) { int t = __ffs(ww) - 1; ww &= ww - 1; memb[p++] = (uint16_t)(lane * 32 + t); }
  __syncthreads();
  for (int i = lane; i < m; i += 64) {
    const float* bp = s_obox + ((size_t)b * KTOP + memb[i]) * 4;
    bx1[i] = bp[0]; by1[i] = bp[1]; bx2[i] = bp[2]; by2[i] = bp[3];
  }
  __syncthreads();
  int nch = (m + 63) >> 6;
  for (int ch = 0; ch < nch; ++ch) {
    int base = ch * 64;
    int my = base + lane;
    bool has = my < m;
    float ax1 = 0, ay1 = 0, ax2 = 0, ay2 = 0, aarea = 0;
    if (has) {
      ax1 = bx1[my]; ay1 = by1[my]; ax2 = bx2[my]; ay2 = by2[my];
      aarea = __fmul_rn(__fsub_rn(ax2, ax1), __fsub_rn(ay2, ay1));
    }
    bool supp = false;
#define IOU_SUPP(j, guard) { \
      float jx1 = bx1[j], jy1 = by1[j], jx2 = bx2[j], jy2 = by2[j]; \
      float jarea = __fmul_rn(__fsub_rn(jx2, jx1), __fsub_rn(jy2, jy1)); \
      float ltx = fmaxf(jx1, ax1), lty = fmaxf(jy1, ay1); \
      float rbx = fminf(jx2, ax2), rby = fminf(jy2, ay2); \
      float wx = fmaxf(__fsub_rn(rbx, ltx), 0.0f); \
      float wy = fmaxf(__fsub_rn(rby, lty), 0.0f); \
      float inter = __fmul_rn(wx, wy); \
      float denom = __fadd_rn(__fsub_rn(__fadd_rn(jarea, aarea), inter), 1e-7f); \
      float iou = __fdiv_rn(inter, denom); \
      supp = supp || ((guard) && iou > IOU_THR); }
    for (int pc = 0; pc < ch; ++pc) {
      uint64_t aw = aliveM[pc];
      while (aw) {
        int e = __ffsll((unsigned long long)aw) - 1; aw &= aw - 1;
        int j = pc * 64 + e;
        IOU_SUPP(j, has)
      }
    }
    uint64_t sm = __ballot(supp);
    int csz = (m - base >= 64) ? 64 : (m - base);
    for (int d = 0; d < csz; ++d) {
      if (!((sm >> d) & 1ull)) {
        int j = base + d;
        IOU_SUPP(j, (lane > d) && has)
        sm = __ballot(supp);
      }
    }
    uint64_t vmask = (csz == 64) ? ~0ull : ((1ull << csz) - 1ull);
    if (lane == 0) aliveM[ch] = (~sm) & vmask;
    __syncthreads();
    if (has && !supp) {
      int rk = memb[my];
      atomicOr(&keepbm[b * 64 + (rk >> 5)], 1u << (rk & 31));
    }
  }
}

// K4: gather + DIRECT write to d_out. Per-batch blocks; slot->rank table
// rebuilt in LDS from keepbm. 16B nontemporal stores, max outstanding writes.
__global__ void __launch_bounds__(256) k_outw(
    const uint32_t* __restrict__ keepbm, const uint32_t* __restrict__ s_n,
    const float* __restrict__ s_score, const float* __restrict__ s_clsf,
    const float* __restrict__ s_box, const float* __restrict__ logits,
    fx4* __restrict__ dout) {
  __shared__ int src[MAXDET];
  int b = blockIdx.x / BPB;
  int jb = blockIdx.x % BPB;
  int tid = threadIdx.x;
  for (int s = tid; s < MAXDET; s += 256) src[s] = -1;
  __syncthreads();
  if (tid < 64) {
    uint32_t keep = keepbm[b * 64 + tid];
    uint32_t cnt = __popc(keep);
    uint32_t scan = cnt;
    for (int d = 1; d < 64; d <<= 1) {
      uint32_t v = __shfl_up(scan, d);
      if (tid >= d) scan += v;
    }
    uint32_t pfx = scan - cnt;
    int lo = tid * 32;
    while (keep) {
      int t = __ffs(keep) - 1;
      keep &= keep - 1;
      if (pfx < MAXDET) src[pfx] = lo + t;
      ++pfx;
    }
  }
  __syncthreads();
  int i = jb * 256 + tid;          // quad index within batch
  if (i >= QPB) return;
  float v0, v1, v2, v3;
#define GETV(k, dst) { \
    int idx = i * 4 + k; \
    int slot = idx / OUTC; \
    int c = idx - slot * OUTC; \
    int r = src[slot]; \
    float x = 0.0f; \
    if (r >= 0) { \
      size_t o = (size_t)b * KTOP + r; \
      if (c < 4) x = s_box[o * 4 + c]; \
      else if (c == 4) x = s_score[o]; \
      else if (c == 5) x = s_clsf[o]; \
      else x = logits[((size_t)b * NDET + s_n[o]) * NCLS + (c - 6)]; \
    } \
    dst = x; }
  GETV(0, v0) GETV(1, v1) GETV(2, v2) GETV(3, v3)
  fx4 f4 = {v0, v1, v2, v3};
  __builtin_nontemporal_store(f4, &dout[(size_t)b * QPB + i]);
}

extern "C" void kernel_launch(void* const* d_in, const int* in_sizes, int n_in,
                              void* d_out, int out_size, void* d_ws, size_t ws_size,
                              hipStream_t stream) {
  const float* pred = (const float*)d_in[0];
  const float* logits = (const float*)d_in[1];

  char* ws = (char*)d_ws;
  size_t off = 0;
  auto alloc = [&](size_t bytes) -> void* {
    void* p = ws + off;
    off += (bytes + 255) & ~(size_t)255;
    return p;
  };
  uint32_t* sw    = (uint32_t*)alloc((size_t)BATCH * NDET * 4);
  uint8_t*  cls8  = (uint8_t*)alloc((size_t)BATCH * NDET);
  uint32_t* s_n   = (uint32_t*)alloc((size_t)BATCH * KTOP * 4);
  float*    s_sc  = (float*)alloc((size_t)BATCH * KTOP * 4);
  float*    s_cl  = (float*)alloc((size_t)BATCH * KTOP * 4);
  uint32_t* clsbm = (uint32_t*)alloc((size_t)BATCH * BMW * 4);
  float*    s_box = (float*)alloc((size_t)BATCH * KTOP * 16);
  float*    s_ob  = (float*)alloc((size_t)BATCH * KTOP * 16);
  uint32_t* keepb = (uint32_t*)alloc((size_t)BATCH * 64 * 4);
  (void)ws_size; (void)in_sizes; (void)n_in;

  k_keys<<<(BATCH * NDET) / 64, 256, 0, stream>>>(pred, sw, cls8);
  k_sel<<<BATCH, 1024, 0, stream>>>(sw, cls8, pred, s_n, s_sc, s_cl, clsbm, s_box, s_ob, keepb);
  k_cnms<<<BATCH * NCLS, 64, 0, stream>>>(clsbm, s_ob, keepb);
  k_outw<<<BATCH * BPB, 256, 0, stream>>>(keepb, s_n, s_sc, s_cl, s_box, logits, (fx4*)d_out);
}

// Round 20
// 83.074 us; speedup vs baseline: 1.5733x; 1.0722x over previous
//
#include <hip/hip_runtime.h>
#include <stdint.h>

#define BATCH 16
#define NDET 25200
#define NCLS 80
#define PREDC 85
#define KTOP 2048
#define MAXDET 300
#define OUTC 86
#define CONF_THR 0.4f
#define IOU_THR 0.45f
#define MAXWH 4096.0f
#define INVHI 0xBF800000u       // ~mono(-1.0f): score word of invalid rows
#define PADHI 0xFFFFFFFFu       // marker for n >= NDET slots (never produced)
#define BMW (NCLS * 64)         // class bitmap words per batch (80 classes x 64)
#define NB 8192                 // histogram bins (13 bits of hi-0x40000000)
#define SIDECAP 2048
#define NITER 25                // ceil(NDET / 1024)
#define QPB ((MAXDET * OUTC) / 4)   // 6450 float4 per batch
#define BPB ((QPB + 255) / 256)     // 26 blocks per batch

typedef float fx4 __attribute__((ext_vector_type(4)));

// ---- monotone float<->uint mapping (ascending) ----
__device__ __forceinline__ uint32_t mono_f32(float f) {
  uint32_t u = __float_as_uint(f);
  return (u & 0x80000000u) ? ~u : (u | 0x80000000u);
}
__device__ __forceinline__ float unmono_f32(uint32_t m) {
  uint32_t u = (m & 0x80000000u) ? (m & 0x7FFFFFFFu) : ~m;
  return __uint_as_float(u);
}

// K1: obj-gated score/argmax, quad (4 lanes) per row.
__global__ void __launch_bounds__(256) k_keys(const float* __restrict__ pred,
                                              uint32_t* __restrict__ sw,
                                              uint8_t* __restrict__ cls8) {
  int gq = blockIdx.x * 64 + (threadIdx.x >> 2);   // 64 rows per block
  int q = threadIdx.x & 3;
  const float* row = pred + (size_t)gq * PREDC;
  float obj = row[4];
  float score = -1.0f;
  uint32_t cl = 0;
  if (obj > CONF_THR) {
    float best = -1e30f;
    int bc = 0;
#pragma unroll
    for (int k = 0; k < 5; ++k) {
#pragma unroll
      for (int j = 0; j < 4; ++j) {
        int c = k * 16 + q * 4 + j;                 // ascending within lane
        float s = __fmul_rn(row[5 + c], obj);       // single-rounded, no contraction
        if (s > best) { best = s; bc = c; }         // strict > : first max
      }
    }
    for (int d = 1; d <= 2; d <<= 1) {              // quad reduce
      float vo = __shfl_xor(best, d);
      int co = __shfl_xor(bc, d);
      if (vo > best || (vo == best && co < bc)) { best = vo; bc = co; }
    }
    if (best > CONF_THR) { score = best; cl = (uint32_t)bc; }
  }
  if (q == 0) {
    sw[gq] = ~mono_f32(score);
    cls8[gq] = (uint8_t)cl;
  }
}

// K2: SINGLE-SCAN selection (round-19 experiment): sw values cached in
// registers during the histogram pass (fully-unrolled fixed-index array,
// rule #20) and the collect pass reuses the cache — one global scan total.
// Then wave-parallel FIND + O(s^2) side ranking + hybrid register/LDS
// bitonic sort + derive (+ class bitmap).
__global__ void __launch_bounds__(1024) k_sel(
    const uint32_t* __restrict__ sw, const uint8_t* __restrict__ cls8,
    const float* __restrict__ pred,
    uint32_t* __restrict__ s_n, float* __restrict__ s_score, float* __restrict__ s_clsf,
    uint32_t* __restrict__ clsbm, float* __restrict__ s_box, float* __restrict__ s_obox,
    uint32_t* __restrict__ keepbm) {
  __shared__ uint64_t sk[KTOP];        // 16 KB
  __shared__ uint64_t side[SIDECAP];   // 16 KB
  __shared__ uint32_t hist[NB];        // 32 KB (reused as class bitmap)
  __shared__ uint32_t sh_dA, ncolM, ncolS;
  int b = blockIdx.x, tid = threadIdx.x, lane = tid & 63;
  const uint32_t* swb = sw + (size_t)b * NDET;
  const uint8_t* clb = cls8 + (size_t)b * NDET;
  if (tid == 0) { ncolM = 0; ncolS = 0; }
  if (tid < 64) keepbm[b * 64 + tid] = 0;
  for (int i = tid; i < NB; i += 1024) hist[i] = 0;
  __syncthreads();

  // ---- ONE global scan: cache sw in registers + build LDS histogram ----
  uint32_t cv[NITER];
#pragma unroll
  for (int i = 0; i < NITER; ++i) {
    int n = tid + i * 1024;
    cv[i] = (n < NDET) ? swb[n] : PADHI;
  }
  {
    uint32_t invcnt = 0;
#pragma unroll
    for (int i = 0; i < NITER; ++i) {
      uint32_t hi = cv[i];
      if (hi == INVHI) ++invcnt;
      else if (hi != PADHI) atomicAdd(&hist[(hi - 0x40000000u) >> 13], 1u);
    }
    for (int d = 1; d < 64; d <<= 1) invcnt += __shfl_xor(invcnt, d);
    if (lane == 0 && invcnt) atomicAdd(&hist[NB - 1], invcnt);
  }
  __syncthreads();

  // ---- wave-parallel FIND: dA = bin containing the 2048th smallest ----
  if (tid < 64) {
    uint32_t segsum = 0;
    for (int i = 0; i < NB / 64; ++i) segsum += hist[lane * (NB / 64) + i];
    uint32_t scan = segsum;
    for (int d = 1; d < 64; d <<= 1) { uint32_t v = __shfl_up(scan, d); if (lane >= d) scan += v; }
    uint32_t excl = scan - segsum;
    bool win = (excl < KTOP) && (KTOP <= scan);
    uint64_t wb = __ballot(win);
    int S = __ffsll((unsigned long long)wb) - 1;
    uint32_t kRem = KTOP - __shfl(excl, S);
    uint32_t v0 = hist[S * (NB / 64) + lane];
    uint32_t v1 = hist[S * (NB / 64) + 64 + lane];
    uint32_t s0 = v0;
    for (int d = 1; d < 64; d <<= 1) { uint32_t v = __shfl_up(s0, d); if (lane >= d) s0 += v; }
    uint32_t tot0 = __shfl(s0, 63);
    uint32_t e0 = s0 - v0;
    uint32_t s1 = v1;
    for (int d = 1; d < 64; d <<= 1) { uint32_t v = __shfl_up(s1, d); if (lane >= d) s1 += v; }
    uint32_t e1 = s1 - v1 + tot0;
    bool w0 = (e0 < kRem) && (kRem <= e0 + v0);
    bool w1 = (e1 < kRem) && (kRem <= e1 + v1);
    uint64_t b0m = __ballot(w0), b1m = __ballot(w1);
    int dA;
    if (b0m) dA = S * (NB / 64) + (__ffsll((unsigned long long)b0m) - 1);
    else     dA = S * (NB / 64) + 64 + (__ffsll((unsigned long long)b1m) - 1);
    if (lane == 0) sh_dA = (uint32_t)dA;
  }
  __syncthreads();
  uint32_t dA = sh_dA;

  // ---- collect from REGISTER cache: main (bin<dA) to sk, side (bin==dA) ----
  // PADHI maps to a huge bin => excluded naturally.
#pragma unroll
  for (int i = 0; i < NITER; ++i) {
    int n = tid + i * 1024;
    uint32_t hi = cv[i];
    uint32_t bin = (hi != INVHI) ? ((hi - 0x40000000u) >> 13) : (NB - 1);
    bool mp = (bin < dA);
    bool sp = (bin == dA);
    uint64_t bm_ = __ballot(mp);
    uint64_t bs_ = __ballot(sp);
    uint32_t baseM = 0, baseS = 0;
    if (lane == 0) {
      if (bm_) baseM = atomicAdd(&ncolM, (uint32_t)__popcll(bm_));
      if (bs_) baseS = atomicAdd(&ncolS, (uint32_t)__popcll(bs_));
    }
    baseM = __shfl(baseM, 0);
    baseS = __shfl(baseS, 0);
    uint64_t lmask = (1ull << lane) - 1ull;
    if (mp) {
      uint64_t key = ((uint64_t)hi << 32) | (((uint32_t)n << 7) | clb[n]);
      sk[baseM + (uint32_t)__popcll(bm_ & lmask)] = key;
    }
    if (sp) {
      uint64_t key = ((uint64_t)hi << 32) | (((uint32_t)n << 7) | clb[n]);
      uint32_t p = baseS + (uint32_t)__popcll(bs_ & lmask);
      if (p < SIDECAP) side[p] = key;
    }
  }
  __syncthreads();

  // ---- side ranking: the (2048-C) smallest side keys fill sk[C..2048) ----
  {
    uint32_t C = ncolM;
    uint32_t s = ncolS; if (s > SIDECAP) s = SIDECAP;
    uint32_t rp = KTOP - C;
    for (uint32_t i = tid; i < s; i += 1024) {
      uint64_t ki = side[i];
      uint32_t rk = 0;
      for (uint32_t j = 0; j < s; ++j) rk += (side[j] < ki) ? 1u : 0u;
      if (rk < rp) sk[C + rk] = ki;
    }
  }
  __syncthreads();

  // ---- hybrid register/LDS bitonic sort (ascending; keys distinct) ----
  {
    int wv = tid >> 6, ln = tid & 63;
    int i1 = wv * 128 + ln;
    int i2 = i1 + 64;
    uint64_t lo = sk[i1], hi = sk[i2];

#define CMPEX_SHFL(j, kk) { \
      uint64_t plo = __shfl_xor((unsigned long long)lo, (j)); \
      uint64_t phi = __shfl_xor((unsigned long long)hi, (j)); \
      bool low1 = ((ln & (j)) == 0); \
      bool km1 = (low1 == ((i1 & (kk)) == 0)); \
      lo = km1 ? (lo < plo ? lo : plo) : (lo > plo ? lo : plo); \
      bool km2 = (low1 == ((i2 & (kk)) == 0)); \
      hi = km2 ? (hi < phi ? hi : phi) : (hi > phi ? hi : phi); }
#define CMPEX_LANE(kk) { \
      bool asc_ = ((i1 & (kk)) == 0); \
      uint64_t mn = lo < hi ? lo : hi; \
      uint64_t mx = lo < hi ? hi : lo; \
      lo = asc_ ? mn : mx; hi = asc_ ? mx : mn; }

    for (int kk = 2; kk <= 128; kk <<= 1) {
      for (int j = kk >> 1; j > 0; j >>= 1) {
        if (j == 64) { CMPEX_LANE(kk) }
        else CMPEX_SHFL(j, kk)
      }
    }
    for (int kk = 256; kk <= KTOP; kk <<= 1) {
      for (int j = kk >> 1; j >= 128; j >>= 1) {
        sk[i1] = lo; sk[i2] = hi;
        __syncthreads();
        uint64_t p1 = sk[i1 ^ j], p2 = sk[i2 ^ j];
        bool km1 = (((i1 & j) == 0) == ((i1 & kk) == 0));
        lo = km1 ? (lo < p1 ? lo : p1) : (lo > p1 ? lo : p1);
        bool km2 = (((i2 & j) == 0) == ((i2 & kk) == 0));
        hi = km2 ? (hi < p2 ? hi : p2) : (hi > p2 ? hi : p2);
        __syncthreads();
      }
      for (int j = 64; j > 0; j >>= 1) {
        if (j == 64) { CMPEX_LANE(kk) }
        else CMPEX_SHFL(j, kk)
      }
    }
    sk[i1] = lo; sk[i2] = hi;
  }
  __syncthreads();

  // ---- class bitmap (reuse hist space; BMW=5120 <= NB) ----
  uint32_t* bm = hist;
  for (int i = tid; i < BMW; i += 1024) bm[i] = 0;
  __syncthreads();

  // ---- derive arrays ----
  for (int rr = tid; rr < KTOP; rr += 1024) {
    uint64_t key = sk[rr];
    float score = unmono_f32(~(uint32_t)(key >> 32));
    uint32_t low = (uint32_t)key;
    uint32_t n = low >> 7;
    uint32_t cls = low & 127u;
    if (score > 0.0f) atomicOr(&bm[cls * 64 + (rr >> 5)], 1u << (rr & 31));
    const float* p = pred + ((size_t)b * NDET + n) * PREDC;
    float x = p[0], y = p[1], w = p[2], h = p[3];
    float hw = __fmul_rn(w, 0.5f), hh = __fmul_rn(h, 0.5f);
    float x1 = __fsub_rn(x, hw), y1 = __fsub_rn(y, hh);
    float x2 = __fadd_rn(x, hw), y2 = __fadd_rn(y, hh);
    float clsf = (float)cls;
    float off = __fmul_rn(clsf, MAXWH);
    size_t o = (size_t)b * KTOP + rr;
    s_n[o] = n;
    s_score[o] = score;
    s_clsf[o] = clsf;
    s_box[o * 4 + 0] = x1; s_box[o * 4 + 1] = y1;
    s_box[o * 4 + 2] = x2; s_box[o * 4 + 3] = y2;
    s_obox[o * 4 + 0] = __fadd_rn(x1, off); s_obox[o * 4 + 1] = __fadd_rn(y1, off);
    s_obox[o * 4 + 2] = __fadd_rn(x2, off); s_obox[o * 4 + 3] = __fadd_rn(y2, off);
  }
  __syncthreads();
  for (int i = tid; i < BMW; i += 1024) clsbm[(size_t)b * BMW + i] = bm[i];
}

// K3: per-(batch,class) greedy NMS (exact decomposition: cross-class IoU == 0).
__global__ void __launch_bounds__(64) k_cnms(
    const uint32_t* __restrict__ clsbm, const float* __restrict__ s_obox,
    uint32_t* __restrict__ keepbm) {
  __shared__ uint16_t memb[KTOP];                 // 4 KB
  __shared__ float bx1[KTOP], by1[KTOP], bx2[KTOP], by2[KTOP];  // 32 KB
  __shared__ uint64_t aliveM[KTOP / 64];
  int b = blockIdx.x / NCLS, c = blockIdx.x % NCLS;
  int lane = threadIdx.x;
  uint32_t w = clsbm[(size_t)b * BMW + c * 64 + lane];
  int cnt = __popc(w);
  int scan = cnt;
  for (int d = 1; d < 64; d <<= 1) {
    int v = __shfl_up(scan, d);
    if (lane >= d) scan += v;
  }
  int m = __shfl(scan, 63);
  if (m == 0) return;
  int p = scan - cnt;
  uint32_t ww = w;
  while (ww) { int t = __ffs(ww) - 1; ww &= ww - 1; memb[p++] = (uint16_t)(lane * 32 + t); }
  __syncthreads();
  for (int i = lane; i < m; i += 64) {
    const float* bp = s_obox + ((size_t)b * KTOP + memb[i]) * 4;
    bx1[i] = bp[0]; by1[i] = bp[1]; bx2[i] = bp[2]; by2[i] = bp[3];
  }
  __syncthreads();
  int nch = (m + 63) >> 6;
  for (int ch = 0; ch < nch; ++ch) {
    int base = ch * 64;
    int my = base + lane;
    bool has = my < m;
    float ax1 = 0, ay1 = 0, ax2 = 0, ay2 = 0, aarea = 0;
    if (has) {
      ax1 = bx1[my]; ay1 = by1[my]; ax2 = bx2[my]; ay2 = by2[my];
      aarea = __fmul_rn(__fsub_rn(ax2, ax1), __fsub_rn(ay2, ay1));
    }
    bool supp = false;
#define IOU_SUPP(j, guard) { \
      float jx1 = bx1[j], jy1 = by1[j], jx2 = bx2[j], jy2 = by2[j]; \
      float jarea = __fmul_rn(__fsub_rn(jx2, jx1), __fsub_rn(jy2, jy1)); \
      float ltx = fmaxf(jx1, ax1), lty = fmaxf(jy1, ay1); \
      float rbx = fminf(jx2, ax2), rby = fminf(jy2, ay2); \
      float wx = fmaxf(__fsub_rn(rbx, ltx), 0.0f); \
      float wy = fmaxf(__fsub_rn(rby, lty), 0.0f); \
      float inter = __fmul_rn(wx, wy); \
      float denom = __fadd_rn(__fsub_rn(__fadd_rn(jarea, aarea), inter), 1e-7f); \
      float iou = __fdiv_rn(inter, denom); \
      supp = supp || ((guard) && iou > IOU_THR); }
    for (int pc = 0; pc < ch; ++pc) {
      uint64_t aw = aliveM[pc];
      while (aw) {
        int e = __ffsll((unsigned long long)aw) - 1; aw &= aw - 1;
        int j = pc * 64 + e;
        IOU_SUPP(j, has)
      }
    }
    uint64_t sm = __ballot(supp);
    int csz = (m - base >= 64) ? 64 : (m - base);
    for (int d = 0; d < csz; ++d) {
      if (!((sm >> d) & 1ull)) {
        int j = base + d;
        IOU_SUPP(j, (lane > d) && has)
        sm = __ballot(supp);
      }
    }
    uint64_t vmask = (csz == 64) ? ~0ull : ((1ull << csz) - 1ull);
    if (lane == 0) aliveM[ch] = (~sm) & vmask;
    __syncthreads();
    if (has && !supp) {
      int rk = memb[my];
      atomicOr(&keepbm[b * 64 + (rk >> 5)], 1u << (rk & 31));
    }
  }
}

// K4: gather + DIRECT write to d_out. Per-batch blocks; slot->rank table
// rebuilt in LDS from keepbm. 16B nontemporal stores, max outstanding writes.
__global__ void __launch_bounds__(256) k_outw(
    const uint32_t* __restrict__ keepbm, const uint32_t* __restrict__ s_n,
    const float* __restrict__ s_score, const float* __restrict__ s_clsf,
    const float* __restrict__ s_box, const float* __restrict__ logits,
    fx4* __restrict__ dout) {
  __shared__ int src[MAXDET];
  int b = blockIdx.x / BPB;
  int jb = blockIdx.x % BPB;
  int tid = threadIdx.x;
  for (int s = tid; s < MAXDET; s += 256) src[s] = -1;
  __syncthreads();
  if (tid < 64) {
    uint32_t keep = keepbm[b * 64 + tid];
    uint32_t cnt = __popc(keep);
    uint32_t scan = cnt;
    for (int d = 1; d < 64; d <<= 1) {
      uint32_t v = __shfl_up(scan, d);
      if (tid >= d) scan += v;
    }
    uint32_t pfx = scan - cnt;
    int lo = tid * 32;
    while (keep) {
      int t = __ffs(keep) - 1;
      keep &= keep - 1;
      if (pfx < MAXDET) src[pfx] = lo + t;
      ++pfx;
    }
  }
  __syncthreads();
  int i = jb * 256 + tid;          // quad index within batch
  if (i >= QPB) return;
  float v0, v1, v2, v3;
#define GETV(k, dst) { \
    int idx = i * 4 + k; \
    int slot = idx / OUTC; \
    int c = idx - slot * OUTC; \
    int r = src[slot]; \
    float x = 0.0f; \
    if (r >= 0) { \
      size_t o = (size_t)b * KTOP + r; \
      if (c < 4) x = s_box[o * 4 + c]; \
      else if (c == 4) x = s_score[o]; \
      else if (c == 5) x = s_clsf[o]; \
      else x = logits[((size_t)b * NDET + s_n[o]) * NCLS + (c - 6)]; \
    } \
    dst = x; }
  GETV(0, v0) GETV(1, v1) GETV(2, v2) GETV(3, v3)
  fx4 f4 = {v0, v1, v2, v3};
  __builtin_nontemporal_store(f4, &dout[(size_t)b * QPB + i]);
}

extern "C" void kernel_launch(void* const* d_in, const int* in_sizes, int n_in,
                              void* d_out, int out_size, void* d_ws, size_t ws_size,
                              hipStream_t stream) {
  const float* pred = (const float*)d_in[0];
  const float* logits = (const float*)d_in[1];

  char* ws = (char*)d_ws;
  size_t off = 0;
  auto alloc = [&](size_t bytes) -> void* {
    void* p = ws + off;
    off += (bytes + 255) & ~(size_t)255;
    return p;
  };
  uint32_t* sw    = (uint32_t*)alloc((size_t)BATCH * NDET * 4);
  uint8_t*  cls8  = (uint8_t*)alloc((size_t)BATCH * NDET);
  uint32_t* s_n   = (uint32_t*)alloc((size_t)BATCH * KTOP * 4);
  float*    s_sc  = (float*)alloc((size_t)BATCH * KTOP * 4);
  float*    s_cl  = (float*)alloc((size_t)BATCH * KTOP * 4);
  uint32_t* clsbm = (uint32_t*)alloc((size_t)BATCH * BMW * 4);
  float*    s_box = (float*)alloc((size_t)BATCH * KTOP * 16);
  float*    s_ob  = (float*)alloc((size_t)BATCH * KTOP * 16);
  uint32_t* keepb = (uint32_t*)alloc((size_t)BATCH * 64 * 4);
  (void)ws_size; (void)in_sizes; (void)n_in;

  k_keys<<<(BATCH * NDET) / 64, 256, 0, stream>>>(pred, sw, cls8);
  k_sel<<<BATCH, 1024, 0, stream>>>(sw, cls8, pred, s_n, s_sc, s_cl, clsbm, s_box, s_ob, keepb);
  k_cnms<<<BATCH * NCLS, 64, 0, stream>>>(clsbm, s_ob, keepb);
  k_outw<<<BATCH * BPB, 256, 0, stream>>>(keepb, s_n, s_sc, s_cl, s_box, logits, (fx4*)d_out);
}

// Round 21
// 82.701 us; speedup vs baseline: 1.5805x; 1.0045x over previous
//
#include <hip/hip_runtime.h>
#include <stdint.h>

#define BATCH 16
#define NDET 25200
#define NCLS 80
#define PREDC 85
#define KTOP 2048
#define MAXDET 300
#define OUTC 86
#define CONF_THR 0.4f
#define IOU_THR 0.45f
#define MAXWH 4096.0f
#define INVHI 0xBF800000u       // ~mono(-1.0f): score word of invalid rows
#define PADHI 0xFFFFFFFFu       // marker for n >= NDET slots (never produced)
#define BMW (NCLS * 64)         // class bitmap words per batch (80 classes x 64)
#define NB 8192                 // histogram bins (13 bits of hi-0x40000000)
#define SIDECAP 2048
#define NITER 25                // ceil(NDET / 1024)
#define QPB ((MAXDET * OUTC) / 4)   // 6450 float4 per batch
#define BPB ((QPB + 255) / 256)     // 26 blocks per batch

typedef float fx4 __attribute__((ext_vector_type(4), aligned(4)));

// ---- monotone float<->uint mapping (ascending) ----
__device__ __forceinline__ uint32_t mono_f32(float f) {
  uint32_t u = __float_as_uint(f);
  return (u & 0x80000000u) ? ~u : (u | 0x80000000u);
}
__device__ __forceinline__ float unmono_f32(uint32_t m) {
  uint32_t u = (m & 0x80000000u) ? (m & 0x7FFFFFFFu) : ~m;
  return __uint_as_float(u);
}

// K1: obj-gated score/argmax, quad (4 lanes) per row. Round-21: per-lane
// class reads are 5 contiguous groups of 4 -> dwordx4 vector loads (4B
// aligned; row offsets are 4 mod 16). Same values, same compare order.
__global__ void __launch_bounds__(256) k_keys(const float* __restrict__ pred,
                                              uint32_t* __restrict__ sw,
                                              uint8_t* __restrict__ cls8) {
  int gq = blockIdx.x * 64 + (threadIdx.x >> 2);   // 64 rows per block
  int q = threadIdx.x & 3;
  const float* row = pred + (size_t)gq * PREDC;
  float obj = row[4];
  float score = -1.0f;
  uint32_t cl = 0;
  if (obj > CONF_THR) {
    float best = -1e30f;
    int bc = 0;
#pragma unroll
    for (int k = 0; k < 5; ++k) {
      fx4 v = *(const fx4*)(row + 5 + q * 4 + k * 16);
#pragma unroll
      for (int j = 0; j < 4; ++j) {
        int c = k * 16 + q * 4 + j;                 // ascending within lane
        float s = __fmul_rn(v[j], obj);             // single-rounded, no contraction
        if (s > best) { best = s; bc = c; }         // strict > : first max
      }
    }
    for (int d = 1; d <= 2; d <<= 1) {              // quad reduce
      float vo = __shfl_xor(best, d);
      int co = __shfl_xor(bc, d);
      if (vo > best || (vo == best && co < bc)) { best = vo; bc = co; }
    }
    if (best > CONF_THR) { score = best; cl = (uint32_t)bc; }
  }
  if (q == 0) {
    sw[gq] = ~mono_f32(score);
    cls8[gq] = (uint8_t)cl;
  }
}

// K2: SINGLE-SCAN selection: sw cached in registers (histogram pass) and
// reused by the collect pass. Wave-parallel FIND + O(s^2) side ranking +
// hybrid register/LDS bitonic sort + derive (fx4 box gather) + class bitmap.
__global__ void __launch_bounds__(1024) k_sel(
    const uint32_t* __restrict__ sw, const uint8_t* __restrict__ cls8,
    const float* __restrict__ pred,
    uint32_t* __restrict__ s_n, float* __restrict__ s_score, float* __restrict__ s_clsf,
    uint32_t* __restrict__ clsbm, float* __restrict__ s_box, float* __restrict__ s_obox,
    uint32_t* __restrict__ keepbm) {
  __shared__ uint64_t sk[KTOP];        // 16 KB
  __shared__ uint64_t side[SIDECAP];   // 16 KB
  __shared__ uint32_t hist[NB];        // 32 KB (reused as class bitmap)
  __shared__ uint32_t sh_dA, ncolM, ncolS;
  int b = blockIdx.x, tid = threadIdx.x, lane = tid & 63;
  const uint32_t* swb = sw + (size_t)b * NDET;
  const uint8_t* clb = cls8 + (size_t)b * NDET;
  if (tid == 0) { ncolM = 0; ncolS = 0; }
  if (tid < 64) keepbm[b * 64 + tid] = 0;
  for (int i = tid; i < NB; i += 1024) hist[i] = 0;
  __syncthreads();

  // ---- ONE global scan: cache sw in registers + build LDS histogram ----
  uint32_t cv[NITER];
#pragma unroll
  for (int i = 0; i < NITER; ++i) {
    int n = tid + i * 1024;
    cv[i] = (n < NDET) ? swb[n] : PADHI;
  }
  {
    uint32_t invcnt = 0;
#pragma unroll
    for (int i = 0; i < NITER; ++i) {
      uint32_t hi = cv[i];
      if (hi == INVHI) ++invcnt;
      else if (hi != PADHI) atomicAdd(&hist[(hi - 0x40000000u) >> 13], 1u);
    }
    for (int d = 1; d < 64; d <<= 1) invcnt += __shfl_xor(invcnt, d);
    if (lane == 0 && invcnt) atomicAdd(&hist[NB - 1], invcnt);
  }
  __syncthreads();

  // ---- wave-parallel FIND: dA = bin containing the 2048th smallest ----
  if (tid < 64) {
    uint32_t segsum = 0;
    for (int i = 0; i < NB / 64; ++i) segsum += hist[lane * (NB / 64) + i];
    uint32_t scan = segsum;
    for (int d = 1; d < 64; d <<= 1) { uint32_t v = __shfl_up(scan, d); if (lane >= d) scan += v; }
    uint32_t excl = scan - segsum;
    bool win = (excl < KTOP) && (KTOP <= scan);
    uint64_t wb = __ballot(win);
    int S = __ffsll((unsigned long long)wb) - 1;
    uint32_t kRem = KTOP - __shfl(excl, S);
    uint32_t v0 = hist[S * (NB / 64) + lane];
    uint32_t v1 = hist[S * (NB / 64) + 64 + lane];
    uint32_t s0 = v0;
    for (int d = 1; d < 64; d <<= 1) { uint32_t v = __shfl_up(s0, d); if (lane >= d) s0 += v; }
    uint32_t tot0 = __shfl(s0, 63);
    uint32_t e0 = s0 - v0;
    uint32_t s1 = v1;
    for (int d = 1; d < 64; d <<= 1) { uint32_t v = __shfl_up(s1, d); if (lane >= d) s1 += v; }
    uint32_t e1 = s1 - v1 + tot0;
    bool w0 = (e0 < kRem) && (kRem <= e0 + v0);
    bool w1 = (e1 < kRem) && (kRem <= e1 + v1);
    uint64_t b0m = __ballot(w0), b1m = __ballot(w1);
    int dA;
    if (b0m) dA = S * (NB / 64) + (__ffsll((unsigned long long)b0m) - 1);
    else     dA = S * (NB / 64) + 64 + (__ffsll((unsigned long long)b1m) - 1);
    if (lane == 0) sh_dA = (uint32_t)dA;
  }
  __syncthreads();
  uint32_t dA = sh_dA;

  // ---- collect from REGISTER cache: main (bin<dA) to sk, side (bin==dA) ----
#pragma unroll
  for (int i = 0; i < NITER; ++i) {
    int n = tid + i * 1024;
    uint32_t hi = cv[i];
    uint32_t bin = (hi != INVHI) ? ((hi - 0x40000000u) >> 13) : (NB - 1);
    bool mp = (bin < dA);
    bool sp = (bin == dA);
    uint64_t bm_ = __ballot(mp);
    uint64_t bs_ = __ballot(sp);
    uint32_t baseM = 0, baseS = 0;
    if (lane == 0) {
      if (bm_) baseM = atomicAdd(&ncolM, (uint32_t)__popcll(bm_));
      if (bs_) baseS = atomicAdd(&ncolS, (uint32_t)__popcll(bs_));
    }
    baseM = __shfl(baseM, 0);
    baseS = __shfl(baseS, 0);
    uint64_t lmask = (1ull << lane) - 1ull;
    if (mp) {
      uint64_t key = ((uint64_t)hi << 32) | (((uint32_t)n << 7) | clb[n]);
      sk[baseM + (uint32_t)__popcll(bm_ & lmask)] = key;
    }
    if (sp) {
      uint64_t key = ((uint64_t)hi << 32) | (((uint32_t)n << 7) | clb[n]);
      uint32_t p = baseS + (uint32_t)__popcll(bs_ & lmask);
      if (p < SIDECAP) side[p] = key;
    }
  }
  __syncthreads();

  // ---- side ranking: the (2048-C) smallest side keys fill sk[C..2048) ----
  {
    uint32_t C = ncolM;
    uint32_t s = ncolS; if (s > SIDECAP) s = SIDECAP;
    uint32_t rp = KTOP - C;
    for (uint32_t i = tid; i < s; i += 1024) {
      uint64_t ki = side[i];
      uint32_t rk = 0;
      for (uint32_t j = 0; j < s; ++j) rk += (side[j] < ki) ? 1u : 0u;
      if (rk < rp) sk[C + rk] = ki;
    }
  }
  __syncthreads();

  // ---- hybrid register/LDS bitonic sort (ascending; keys distinct) ----
  {
    int wv = tid >> 6, ln = tid & 63;
    int i1 = wv * 128 + ln;
    int i2 = i1 + 64;
    uint64_t lo = sk[i1], hi = sk[i2];

#define CMPEX_SHFL(j, kk) { \
      uint64_t plo = __shfl_xor((unsigned long long)lo, (j)); \
      uint64_t phi = __shfl_xor((unsigned long long)hi, (j)); \
      bool low1 = ((ln & (j)) == 0); \
      bool km1 = (low1 == ((i1 & (kk)) == 0)); \
      lo = km1 ? (lo < plo ? lo : plo) : (lo > plo ? lo : plo); \
      bool km2 = (low1 == ((i2 & (kk)) == 0)); \
      hi = km2 ? (hi < phi ? hi : phi) : (hi > phi ? hi : phi); }
#define CMPEX_LANE(kk) { \
      bool asc_ = ((i1 & (kk)) == 0); \
      uint64_t mn = lo < hi ? lo : hi; \
      uint64_t mx = lo < hi ? hi : lo; \
      lo = asc_ ? mn : mx; hi = asc_ ? mx : mn; }

    for (int kk = 2; kk <= 128; kk <<= 1) {
      for (int j = kk >> 1; j > 0; j >>= 1) {
        if (j == 64) { CMPEX_LANE(kk) }
        else CMPEX_SHFL(j, kk)
      }
    }
    for (int kk = 256; kk <= KTOP; kk <<= 1) {
      for (int j = kk >> 1; j >= 128; j >>= 1) {
        sk[i1] = lo; sk[i2] = hi;
        __syncthreads();
        uint64_t p1 = sk[i1 ^ j], p2 = sk[i2 ^ j];
        bool km1 = (((i1 & j) == 0) == ((i1 & kk) == 0));
        lo = km1 ? (lo < p1 ? lo : p1) : (lo > p1 ? lo : p1);
        bool km2 = (((i2 & j) == 0) == ((i2 & kk) == 0));
        hi = km2 ? (hi < p2 ? hi : p2) : (hi > p2 ? hi : p2);
        __syncthreads();
      }
      for (int j = 64; j > 0; j >>= 1) {
        if (j == 64) { CMPEX_LANE(kk) }
        else CMPEX_SHFL(j, kk)
      }
    }
    sk[i1] = lo; sk[i2] = hi;
  }
  __syncthreads();

  // ---- class bitmap (reuse hist space; BMW=5120 <= NB) ----
  uint32_t* bm = hist;
  for (int i = tid; i < BMW; i += 1024) bm[i] = 0;
  __syncthreads();

  // ---- derive arrays (fx4 box gather: 1 request/row instead of 4) ----
  for (int rr = tid; rr < KTOP; rr += 1024) {
    uint64_t key = sk[rr];
    float score = unmono_f32(~(uint32_t)(key >> 32));
    uint32_t low = (uint32_t)key;
    uint32_t n = low >> 7;
    uint32_t cls = low & 127u;
    if (score > 0.0f) atomicOr(&bm[cls * 64 + (rr >> 5)], 1u << (rr & 31));
    const float* p = pred + ((size_t)b * NDET + n) * PREDC;
    fx4 xywh = *(const fx4*)p;
    float x = xywh[0], y = xywh[1], w = xywh[2], h = xywh[3];
    float hw = __fmul_rn(w, 0.5f), hh = __fmul_rn(h, 0.5f);
    float x1 = __fsub_rn(x, hw), y1 = __fsub_rn(y, hh);
    float x2 = __fadd_rn(x, hw), y2 = __fadd_rn(y, hh);
    float clsf = (float)cls;
    float off = __fmul_rn(clsf, MAXWH);
    size_t o = (size_t)b * KTOP + rr;
    s_n[o] = n;
    s_score[o] = score;
    s_clsf[o] = clsf;
    s_box[o * 4 + 0] = x1; s_box[o * 4 + 1] = y1;
    s_box[o * 4 + 2] = x2; s_box[o * 4 + 3] = y2;
    s_obox[o * 4 + 0] = __fadd_rn(x1, off); s_obox[o * 4 + 1] = __fadd_rn(y1, off);
    s_obox[o * 4 + 2] = __fadd_rn(x2, off); s_obox[o * 4 + 3] = __fadd_rn(y2, off);
  }
  __syncthreads();
  for (int i = tid; i < BMW; i += 1024) clsbm[(size_t)b * BMW + i] = bm[i];
}

// K3: per-(batch,class) greedy NMS (exact decomposition: cross-class IoU == 0).
__global__ void __launch_bounds__(64) k_cnms(
    const uint32_t* __restrict__ clsbm, const float* __restrict__ s_obox,
    uint32_t* __restrict__ keepbm) {
  __shared__ uint16_t memb[KTOP];                 // 4 KB
  __shared__ float bx1[KTOP], by1[KTOP], bx2[KTOP], by2[KTOP];  // 32 KB
  __shared__ uint64_t aliveM[KTOP / 64];
  int b = blockIdx.x / NCLS, c = blockIdx.x % NCLS;
  int lane = threadIdx.x;
  uint32_t w = clsbm[(size_t)b * BMW + c * 64 + lane];
  int cnt = __popc(w);
  int scan = cnt;
  for (int d = 1; d < 64; d <<= 1) {
    int v = __shfl_up(scan, d);
    if (lane >= d) scan += v;
  }
  int m = __shfl(scan, 63);
  if (m == 0) return;
  int p = scan - cnt;
  uint32_t ww = w;
  while (ww) { int t = __ffs(ww) - 1; ww &= ww - 1; memb[p++] = (uint16_t)(lane * 32 + t); }
  __syncthreads();
  for (int i = lane; i < m; i += 64) {
    const float* bp = s_obox + ((size_t)b * KTOP + memb[i]) * 4;
    bx1[i] = bp[0]; by1[i] = bp[1]; bx2[i] = bp[2]; by2[i] = bp[3];
  }
  __syncthreads();
  int nch = (m + 63) >> 6;
  for (int ch = 0; ch < nch; ++ch) {
    int base = ch * 64;
    int my = base + lane;
    bool has = my < m;
    float ax1 = 0, ay1 = 0, ax2 = 0, ay2 = 0, aarea = 0;
    if (has) {
      ax1 = bx1[my]; ay1 = by1[my]; ax2 = bx2[my]; ay2 = by2[my];
      aarea = __fmul_rn(__fsub_rn(ax2, ax1), __fsub_rn(ay2, ay1));
    }
    bool supp = false;
#define IOU_SUPP(j, guard) { \
      float jx1 = bx1[j], jy1 = by1[j], jx2 = bx2[j], jy2 = by2[j]; \
      float jarea = __fmul_rn(__fsub_rn(jx2, jx1), __fsub_rn(jy2, jy1)); \
      float ltx = fmaxf(jx1, ax1), lty = fmaxf(jy1, ay1); \
      float rbx = fminf(jx2, ax2), rby = fminf(jy2, ay2); \
      float wx = fmaxf(__fsub_rn(rbx, ltx), 0.0f); \
      float wy = fmaxf(__fsub_rn(rby, lty), 0.0f); \
      float inter = __fmul_rn(wx, wy); \
      float denom = __fadd_rn(__fsub_rn(__fadd_rn(jarea, aarea), inter), 1e-7f); \
      float iou = __fdiv_rn(inter, denom); \
      supp = supp || ((guard) && iou > IOU_THR); }
    for (int pc = 0; pc < ch; ++pc) {
      uint64_t aw = aliveM[pc];
      while (aw) {
        int e = __ffsll((unsigned long long)aw) - 1; aw &= aw - 1;
        int j = pc * 64 + e;
        IOU_SUPP(j, has)
      }
    }
    uint64_t sm = __ballot(supp);
    int csz = (m - base >= 64) ? 64 : (m - base);
    for (int d = 0; d < csz; ++d) {
      if (!((sm >> d) & 1ull)) {
        int j = base + d;
        IOU_SUPP(j, (lane > d) && has)
        sm = __ballot(supp);
      }
    }
    uint64_t vmask = (csz == 64) ? ~0ull : ((1ull << csz) - 1ull);
    if (lane == 0) aliveM[ch] = (~sm) & vmask;
    __syncthreads();
    if (has && !supp) {
      int rk = memb[my];
      atomicOr(&keepbm[b * 64 + (rk >> 5)], 1u << (rk & 31));
    }
  }
}

// K4: gather + DIRECT write to d_out. Per-batch blocks; slot->rank table
// rebuilt in LDS from keepbm. 16B nontemporal stores, max outstanding writes.
__global__ void __launch_bounds__(256) k_outw(
    const uint32_t* __restrict__ keepbm, const uint32_t* __restrict__ s_n,
    const float* __restrict__ s_score, const float* __restrict__ s_clsf,
    const float* __restrict__ s_box, const float* __restrict__ logits,
    fx4* __restrict__ dout) {
  __shared__ int src[MAXDET];
  int b = blockIdx.x / BPB;
  int jb = blockIdx.x % BPB;
  int tid = threadIdx.x;
  for (int s = tid; s < MAXDET; s += 256) src[s] = -1;
  __syncthreads();
  if (tid < 64) {
    uint32_t keep = keepbm[b * 64 + tid];
    uint32_t cnt = __popc(keep);
    uint32_t scan = cnt;
    for (int d = 1; d < 64; d <<= 1) {
      uint32_t v = __shfl_up(scan, d);
      if (tid >= d) scan += v;
    }
    uint32_t pfx = scan - cnt;
    int lo = tid * 32;
    while (keep) {
      int t = __ffs(keep) - 1;
      keep &= keep - 1;
      if (pfx < MAXDET) src[pfx] = lo + t;
      ++pfx;
    }
  }
  __syncthreads();
  int i = jb * 256 + tid;          // quad index within batch
  if (i >= QPB) return;
  float v0, v1, v2, v3;
#define GETV(k, dst) { \
    int idx = i * 4 + k; \
    int slot = idx / OUTC; \
    int c = idx - slot * OUTC; \
    int r = src[slot]; \
    float x = 0.0f; \
    if (r >= 0) { \
      size_t o = (size_t)b * KTOP + r; \
      if (c < 4) x = s_box[o * 4 + c]; \
      else if (c == 4) x = s_score[o]; \
      else if (c == 5) x = s_clsf[o]; \
      else x = logits[((size_t)b * NDET + s_n[o]) * NCLS + (c - 6)]; \
    } \
    dst = x; }
  GETV(0, v0) GETV(1, v1) GETV(2, v2) GETV(3, v3)
  fx4 f4 = {v0, v1, v2, v3};
  __builtin_nontemporal_store(f4, &dout[(size_t)b * QPB + i]);
}

extern "C" void kernel_launch(void* const* d_in, const int* in_sizes, int n_in,
                              void* d_out, int out_size, void* d_ws, size_t ws_size,
                              hipStream_t stream) {
  const float* pred = (const float*)d_in[0];
  const float* logits = (const float*)d_in[1];

  char* ws = (char*)d_ws;
  size_t off = 0;
  auto alloc = [&](size_t bytes) -> void* {
    void* p = ws + off;
    off += (bytes + 255) & ~(size_t)255;
    return p;
  };
  uint32_t* sw    = (uint32_t*)alloc((size_t)BATCH * NDET * 4);
  uint8_t*  cls8  = (uint8_t*)alloc((size_t)BATCH * NDET);
  uint32_t* s_n   = (uint32_t*)alloc((size_t)BATCH * KTOP * 4);
  float*    s_sc  = (float*)alloc((size_t)BATCH * KTOP * 4);
  float*    s_cl  = (float*)alloc((size_t)BATCH * KTOP * 4);
  uint32_t* clsbm = (uint32_t*)alloc((size_t)BATCH * BMW * 4);
  float*    s_box = (float*)alloc((size_t)BATCH * KTOP * 16);
  float*    s_ob  = (float*)alloc((size_t)BATCH * KTOP * 16);
  uint32_t* keepb = (uint32_t*)alloc((size_t)BATCH * 64 * 4);
  (void)ws_size; (void)in_sizes; (void)n_in;

  k_keys<<<(BATCH * NDET) / 64, 256, 0, stream>>>(pred, sw, cls8);
  k_sel<<<BATCH, 1024, 0, stream>>>(sw, cls8, pred, s_n, s_sc, s_cl, clsbm, s_box, s_ob, keepb);
  k_cnms<<<BATCH * NCLS, 64, 0, stream>>>(clsbm, s_ob, keepb);
  k_outw<<<BATCH * BPB, 256, 0, stream>>>(keepb, s_n, s_sc, s_cl, s_box, logits, (fx4*)d_out);
}